// Round 1
// baseline (1662.576 us; speedup 1.0000x reference)
//
#include <hip/hip_runtime.h>
#include <math.h>

#define DIMX 2048
#define KV_RANK 512
#define Q_RANK 768
#define NH 16
#define D_NR 128
#define D_R 64
#define D_V 128
#define NB 8
#define NL 32
#define MAX_T 4096
#define STARTP (MAX_T - NL)      /* 4064 */
#define QK_DIM (D_NR + D_R)      /* 192 */
#define ATT_SCALE 0.07216878364870323f  /* 1/sqrt(192) */
#define RMS_EPS 1.1920929e-07f

// ---------------------------------------------------------------------------
// Generic batched tiled fp32 GEMM: C = A * op(B), reduce over K.
// BT=true : B stored row-major as (N,K)  -> C[m][n] = sum_k A[m][k]*B[n][k]
// BT=false: B stored row-major as (K,N)  -> C[m][n] = sum_k A[m][k]*B[k][n]
// 32x32 tile, 256 threads, each thread computes a 2x2 micro-tile.
// Batch: blockIdx.z -> (z1 = z / nb2, z2 = z % nb2), pointer offsets applied.
// All M,N,K are multiples of 32 in this problem (no edge guards).
// ---------------------------------------------------------------------------
template<bool BT, bool ACC>
__global__ __launch_bounds__(256) void gemm32(
    const float* __restrict__ A, const float* __restrict__ Bm, float* __restrict__ C,
    int M, int N, int K, int lda, int ldb, int ldc,
    long long sA1, long long sA2, long long sB1, long long sB2,
    long long sC1, long long sC2, int nb2)
{
    int z = blockIdx.z;
    int z1 = z / nb2, z2 = z % nb2;
    A += z1 * sA1 + z2 * sA2;
    Bm += z1 * sB1 + z2 * sB2;
    C += z1 * sC1 + z2 * sC2;

    __shared__ float As[32][33];
    __shared__ float Bs[32][33];

    const int m0 = blockIdx.y * 32;
    const int n0 = blockIdx.x * 32;
    const int tid = threadIdx.x;
    const int ty = tid >> 4;      // 0..15
    const int tx = tid & 15;      // 0..15

    float acc00 = 0.f, acc01 = 0.f, acc10 = 0.f, acc11 = 0.f;

    for (int k0 = 0; k0 < K; k0 += 32) {
        #pragma unroll
        for (int i = 0; i < 4; ++i) {
            int idx = tid + i * 256;
            int r = idx >> 5, c = idx & 31;
            As[r][c] = A[(long long)(m0 + r) * lda + (k0 + c)];
        }
        #pragma unroll
        for (int i = 0; i < 4; ++i) {
            int idx = tid + i * 256;
            if (BT) {
                int n = idx >> 5, kk = idx & 31;
                Bs[kk][n] = Bm[(long long)(n0 + n) * ldb + (k0 + kk)];
            } else {
                int kk = idx >> 5, n = idx & 31;
                Bs[kk][n] = Bm[(long long)(k0 + kk) * ldb + (n0 + n)];
            }
        }
        __syncthreads();
        #pragma unroll
        for (int kk = 0; kk < 32; ++kk) {
            float a0 = As[ty][kk];
            float a1 = As[ty + 16][kk];
            float b0 = Bs[kk][tx];
            float b1 = Bs[kk][tx + 16];
            acc00 += a0 * b0; acc01 += a0 * b1;
            acc10 += a1 * b0; acc11 += a1 * b1;
        }
        __syncthreads();
    }

    long long r0 = (long long)(m0 + ty) * ldc + n0;
    long long r1 = (long long)(m0 + ty + 16) * ldc + n0;
    if (ACC) {
        C[r0 + tx]      += acc00;
        C[r0 + tx + 16] += acc01;
        C[r1 + tx]      += acc10;
        C[r1 + tx + 16] += acc11;
    } else {
        C[r0 + tx]      = acc00;
        C[r0 + tx + 16] = acc01;
        C[r1 + tx]      = acc10;
        C[r1 + tx + 16] = acc11;
    }
}

// RMS norm over rows of length 768, in place, times weight.
__global__ __launch_bounds__(256) void rms_kernel(float* __restrict__ qd,
                                                  const float* __restrict__ w)
{
    const int row = blockIdx.x;           // 0..255
    float* p = qd + (long long)row * Q_RANK;
    __shared__ float red[256];
    float s = 0.f;
    for (int i = threadIdx.x; i < Q_RANK; i += 256) { float v = p[i]; s += v * v; }
    red[threadIdx.x] = s;
    __syncthreads();
    for (int off = 128; off > 0; off >>= 1) {
        if (threadIdx.x < off) red[threadIdx.x] += red[threadIdx.x + off];
        __syncthreads();
    }
    float scale = rsqrtf(red[0] / (float)Q_RANK + RMS_EPS);
    for (int i = threadIdx.x; i < Q_RANK; i += 256) p[i] = p[i] * scale * w[i];
}

// Write kv_latent rows + roped k_rope rows into the caches (rows START..START+31).
__global__ __launch_bounds__(256) void cache_update(const float* __restrict__ kv,
                                                    const float* __restrict__ fc,
                                                    const float* __restrict__ fs,
                                                    float* __restrict__ kvc,
                                                    float* __restrict__ krc)
{
    const int bl = blockIdx.x;            // 0..255
    const int b = bl >> 5, l = bl & 31;
    const float* row = kv + (long long)bl * (KV_RANK + D_R);
    const int t = STARTP + l;
    float* dst = kvc + ((long long)b * MAX_T + t) * KV_RANK;
    for (int i = threadIdx.x; i < KV_RANK; i += 256) dst[i] = row[i];
    if (threadIdx.x < D_R / 2) {
        int i = threadIdx.x;
        float xr = row[KV_RANK + 2 * i];
        float xi = row[KV_RANK + 2 * i + 1];
        float c = fc[l * (D_R / 2) + i];
        float s = fs[l * (D_R / 2) + i];
        float* kd = krc + ((long long)b * MAX_T + t) * D_R;
        kd[2 * i]     = xr * c - xi * s;
        kd[2 * i + 1] = xr * s + xi * c;
    }
}

// Apply RoPE to q_rope and scatter into qprime[b,h,l,512:576].
__global__ __launch_bounds__(256) void rope_q(const float* __restrict__ q,
                                              const float* __restrict__ fc,
                                              const float* __restrict__ fs,
                                              float* __restrict__ qprime)
{
    int idx = blockIdx.x * 256 + threadIdx.x;   // NB*NL*NH*32 = 131072
    int i = idx & 31;
    int h = (idx >> 5) & (NH - 1);
    int l = (idx >> 9) & (NL - 1);
    int b = idx >> 14;
    const float* src = q + ((long long)(b * NL + l) * NH + h) * QK_DIM + D_NR + 2 * i;
    float xr = src[0], xi = src[1];
    float c = fc[l * (D_R / 2) + i];
    float s = fs[l * (D_R / 2) + i];
    float* dst = qprime + ((long long)(b * NH + h) * NL + l) * (KV_RANK + D_R) + KV_RANK + 2 * i;
    dst[0] = xr * c - xi * s;
    dst[1] = xr * s + xi * c;
}

// Row softmax with causal masking by index; invalid tail zeroed. In place.
__global__ __launch_bounds__(256) void softmax_kernel(float* __restrict__ scores)
{
    const int row = blockIdx.x;     // b*512 + h*32 + l
    const int l = row & 31;
    const int vlen = STARTP + l + 1;
    float* s = scores + (long long)row * MAX_T;
    __shared__ float red[256];

    float m = -1e30f;
    for (int t = threadIdx.x; t < vlen; t += 256) m = fmaxf(m, s[t]);
    red[threadIdx.x] = m;
    __syncthreads();
    for (int off = 128; off > 0; off >>= 1) {
        if (threadIdx.x < off) red[threadIdx.x] = fmaxf(red[threadIdx.x], red[threadIdx.x + off]);
        __syncthreads();
    }
    m = red[0] * ATT_SCALE;
    __syncthreads();

    float sum = 0.f;
    for (int t = threadIdx.x; t < vlen; t += 256) {
        float p = expf(s[t] * ATT_SCALE - m);
        s[t] = p;
        sum += p;
    }
    red[threadIdx.x] = sum;
    __syncthreads();
    for (int off = 128; off > 0; off >>= 1) {
        if (threadIdx.x < off) red[threadIdx.x] += red[threadIdx.x + off];
        __syncthreads();
    }
    float inv = 1.0f / red[0];
    for (int t = threadIdx.x; t < MAX_T; t += 256) {
        if (t < vlen) s[t] *= inv;
        else s[t] = 0.f;
    }
}

extern "C" void kernel_launch(void* const* d_in, const int* in_sizes, int n_in,
                              void* d_out, int out_size, void* d_ws, size_t ws_size,
                              hipStream_t stream)
{
    const float* x        = (const float*)d_in[0];
    const float* fc       = (const float*)d_in[2];
    const float* fs       = (const float*)d_in[3];
    float* kvc            = (float*)d_in[5];   // written in place (harness restores inputs)
    float* krc            = (float*)d_in[6];
    const float* w_kv_down= (const float*)d_in[7];
    const float* w_q_down = (const float*)d_in[8];
    const float* rms_q_w  = (const float*)d_in[9];
    const float* w_q_up   = (const float*)d_in[10];
    const float* w_kv_up  = (const float*)d_in[11];
    const float* w_out    = (const float*)d_in[12];
    float* out            = (float*)d_out;

    float* ws = (float*)d_ws;
    float* q_down  = ws;                                   // 256 x 768
    float* q       = q_down + 256 * 768;                   // 256 x 3072
    float* kv      = q + 256 * 3072;                       // 256 x 576
    float* qprime  = kv + 256 * 576;                       // (b,h,l,576)
    float* scores  = qprime + (long long)NB * NH * NL * 576;   // (b,h*l,4096)
    float* o_heads = scores + (long long)NB * NH * NL * MAX_T; // (b,h,l,512)
    float* o_up    = o_heads + (long long)NB * NH * NL * KV_RANK; // 256 x 2048

    // 1) q_down = x @ w_q_down^T        (256,768,2048)
    gemm32<true, false><<<dim3(768 / 32, 256 / 32, 1), 256, 0, stream>>>(
        x, w_q_down, q_down, 256, 768, 2048, 2048, 2048, 768,
        0, 0, 0, 0, 0, 0, 1);

    // 2) RMS norm in place
    rms_kernel<<<256, 256, 0, stream>>>(q_down, rms_q_w);

    // 3) q = q_down @ w_q_up^T          (256,3072,768)
    gemm32<true, false><<<dim3(3072 / 32, 256 / 32, 1), 256, 0, stream>>>(
        q_down, w_q_up, q, 256, 3072, 768, 768, 768, 3072,
        0, 0, 0, 0, 0, 0, 1);

    // 4) kv = x @ w_kv_down^T           (256,576,2048)
    gemm32<true, false><<<dim3(576 / 32, 256 / 32, 1), 256, 0, stream>>>(
        x, w_kv_down, kv, 256, 576, 2048, 2048, 2048, 576,
        0, 0, 0, 0, 0, 0, 1);

    // 5) cache update (latent copy + roped k_rope) into input caches
    cache_update<<<256, 256, 0, stream>>>(kv, fc, fs, kvc, krc);

    // 6) roped q_rope -> qprime[...,512:576]
    rope_q<<<(NB * NL * NH * 32) / 256, 256, 0, stream>>>(q, fc, fs, qprime);

    // 7) q_abs: per (b,h) GEMM (32,512,128) -> qprime[...,0:512]
    gemm32<false, false><<<dim3(512 / 32, 1, NB * NH), 256, 0, stream>>>(
        q, w_kv_up, qprime, 32, 512, 128, 3072, 512, 576,
        (long long)NL * NH * QK_DIM * NL / NL * 96 /*unused form*/ * 0 + (long long)32 * 3072, 192,
        0, (long long)256 * 512,
        (long long)NH * NL * 576, (long long)NL * 576, NH);

    // 8) scores = Qabs @ kvc^T per b    (512,4096,512)
    gemm32<true, false><<<dim3(MAX_T / 32, 512 / 32, NB), 256, 0, stream>>>(
        qprime, kvc, scores, 512, MAX_T, 512, 576, 512, MAX_T,
        (long long)512 * 576, 0, (long long)MAX_T * KV_RANK, 0,
        (long long)512 * MAX_T, 0, 1);

    // 9) scores += Qrope @ krc^T per b  (512,4096,64)
    gemm32<true, true><<<dim3(MAX_T / 32, 512 / 32, NB), 256, 0, stream>>>(
        qprime + 512, krc, scores, 512, MAX_T, 64, 576, 64, MAX_T,
        (long long)512 * 576, 0, (long long)MAX_T * D_R, 0,
        (long long)512 * MAX_T, 0, 1);

    // 10) softmax rows (scale+mask inside)
    softmax_kernel<<<NB * NH * NL, 256, 0, stream>>>(scores);

    // 11) o_heads = P @ kvc per b       (512,512,4096), B not transposed
    gemm32<false, false><<<dim3(512 / 32, 512 / 32, NB), 256, 0, stream>>>(
        scores, kvc, o_heads, 512, 512, MAX_T, MAX_T, 512, 512,
        (long long)512 * MAX_T, 0, (long long)MAX_T * KV_RANK, 0,
        (long long)512 * 512, 0, 1);

    // 12) o_up: per (b,h) GEMM (32,128,512) with W_UV
    gemm32<true, false><<<dim3(128 / 32, 1, NB * NH), 256, 0, stream>>>(
        o_heads, w_kv_up + 128 * 512, o_up, 32, 128, 512, 512, 512, 2048,
        (long long)NH * NL * 512, (long long)NL * 512,
        0, (long long)256 * 512,
        (long long)NL * 2048, 128, NH);

    // 13) out = o_up @ w_out^T          (256,2048,2048)
    gemm32<true, false><<<dim3(2048 / 32, 256 / 32, 1), 256, 0, stream>>>(
        o_up, w_out, out, 256, 2048, 2048, 2048, 2048, 2048,
        0, 0, 0, 0, 0, 0, 1);
}

// Round 2
// 453.489 us; speedup vs baseline: 3.6662x; 3.6662x over previous
//
#include <hip/hip_runtime.h>
#include <math.h>

#define DIMX 2048
#define KV_RANK 512
#define Q_RANK 768
#define NH 16
#define D_NR 128
#define D_R 64
#define D_V 128
#define NB 8
#define NL 32
#define MAX_T 4096
#define STARTP (MAX_T - NL)      /* 4064 */
#define QK_DIM (D_NR + D_R)      /* 192 */
#define ATT_SCALE 0.07216878364870323f  /* 1/sqrt(192) */
#define RMS_EPS 1.1920929e-07f

typedef unsigned short u16;
typedef __attribute__((ext_vector_type(4))) unsigned short u16x4;
typedef __attribute__((ext_vector_type(8))) short short8;
typedef __attribute__((ext_vector_type(4))) float f32x4;

#define GLOBAL_AS __attribute__((address_space(1)))
#define LDS_AS __attribute__((address_space(3)))

__device__ inline u16 f2b(float f) {
    union { float f; unsigned u; } v; v.f = f;
    unsigned r = (v.u + 0x7fffu + ((v.u >> 16) & 1u)) >> 16;
    return (u16)r;
}

// ---------------------------------------------------------------------------
// bf16 MFMA GEMM, C = A * B^T (both A and B row-major (rows, K)), fp32 out.
// BM x BN tile, 4 waves in 2x2 grid, each wave MFRx NFR fragments of 16x16.
// K staged in BK=32 slices via global_load_lds (16B/lane, linear LDS).
// Requires: M % BM == 0, N % BN == 0, K % 32 == 0, lda/ldb multiples of 8.
// ---------------------------------------------------------------------------
template<int BM, int BN, int MFR, int NFR>
__global__ __launch_bounds__(256) void gemm_mfma(
    const u16* __restrict__ A, const u16* __restrict__ B, float* __restrict__ C,
    int K, int lda, int ldb, int ldc,
    long long sA, long long sB, long long sC)
{
    const int z = blockIdx.z;
    A += z * sA; B += z * sB; C += z * sC;
    const int m0 = blockIdx.y * BM;
    const int n0 = blockIdx.x * BN;
    const int tid = threadIdx.x;
    const int lane = tid & 63;
    const int wid = tid >> 6;
    const int wm = wid >> 1, wn = wid & 1;
    const int l15 = lane & 15;
    const int l4  = lane >> 4;

    __shared__ __align__(16) u16 As[BM * 32];
    __shared__ __align__(16) u16 Bs[BN * 32];

    f32x4 acc[MFR][NFR];
    #pragma unroll
    for (int i = 0; i < MFR; ++i)
        #pragma unroll
        for (int j = 0; j < NFR; ++j)
            acc[i][j] = (f32x4)0.0f;

    for (int k0 = 0; k0 < K; k0 += 32) {
        #pragma unroll
        for (int i = 0; i < BM / 64; ++i) {
            int c = (wid * (BM / 64) + i) * 64 + lane;      // 16B chunk id
            const u16* src = A + (long long)(m0 + (c >> 2)) * lda + k0 + (c & 3) * 8;
            u16* dst = &As[(wid * (BM / 64) + i) * 512];    // wave-uniform base
            __builtin_amdgcn_global_load_lds((const GLOBAL_AS void*)src,
                                             (LDS_AS void*)dst, 16, 0, 0);
        }
        #pragma unroll
        for (int i = 0; i < BN / 64; ++i) {
            int c = (wid * (BN / 64) + i) * 64 + lane;
            const u16* src = B + (long long)(n0 + (c >> 2)) * ldb + k0 + (c & 3) * 8;
            u16* dst = &Bs[(wid * (BN / 64) + i) * 512];
            __builtin_amdgcn_global_load_lds((const GLOBAL_AS void*)src,
                                             (LDS_AS void*)dst, 16, 0, 0);
        }
        __syncthreads();

        short8 a[MFR], b[NFR];
        #pragma unroll
        for (int mf = 0; mf < MFR; ++mf)
            a[mf] = *(const short8*)&As[(wm * 16 * MFR + mf * 16 + l15) * 32 + l4 * 8];
        #pragma unroll
        for (int nf = 0; nf < NFR; ++nf)
            b[nf] = *(const short8*)&Bs[(wn * 16 * NFR + nf * 16 + l15) * 32 + l4 * 8];
        #pragma unroll
        for (int mf = 0; mf < MFR; ++mf)
            #pragma unroll
            for (int nf = 0; nf < NFR; ++nf)
                acc[mf][nf] = __builtin_amdgcn_mfma_f32_16x16x32_bf16(
                    a[mf], b[nf], acc[mf][nf], 0, 0, 0);
        __syncthreads();
    }

    #pragma unroll
    for (int mf = 0; mf < MFR; ++mf) {
        #pragma unroll
        for (int nf = 0; nf < NFR; ++nf) {
            int r0 = m0 + wm * 16 * MFR + mf * 16 + l4 * 4;
            int c0 = n0 + wn * 16 * NFR + nf * 16 + l15;
            #pragma unroll
            for (int r = 0; r < 4; ++r)
                C[(long long)(r0 + r) * ldc + c0] = acc[mf][nf][r];
        }
    }
}

// ---------------------------------------------------------------------------
// fp32 fallback GEMM (per-head small GEMMs), from round 0.
// ---------------------------------------------------------------------------
template<bool BT, bool ACC>
__global__ __launch_bounds__(256) void gemm32(
    const float* __restrict__ A, const float* __restrict__ Bm, float* __restrict__ C,
    int M, int N, int K, int lda, int ldb, int ldc,
    long long sA1, long long sA2, long long sB1, long long sB2,
    long long sC1, long long sC2, int nb2)
{
    int z = blockIdx.z;
    int z1 = z / nb2, z2 = z % nb2;
    A += z1 * sA1 + z2 * sA2;
    Bm += z1 * sB1 + z2 * sB2;
    C += z1 * sC1 + z2 * sC2;

    __shared__ float As[32][33];
    __shared__ float Bs[32][33];

    const int m0 = blockIdx.y * 32;
    const int n0 = blockIdx.x * 32;
    const int tid = threadIdx.x;
    const int ty = tid >> 4;
    const int tx = tid & 15;

    float acc00 = 0.f, acc01 = 0.f, acc10 = 0.f, acc11 = 0.f;

    for (int k0 = 0; k0 < K; k0 += 32) {
        #pragma unroll
        for (int i = 0; i < 4; ++i) {
            int idx = tid + i * 256;
            int r = idx >> 5, c = idx & 31;
            As[r][c] = A[(long long)(m0 + r) * lda + (k0 + c)];
        }
        #pragma unroll
        for (int i = 0; i < 4; ++i) {
            int idx = tid + i * 256;
            if (BT) {
                int n = idx >> 5, kk = idx & 31;
                Bs[kk][n] = Bm[(long long)(n0 + n) * ldb + (k0 + kk)];
            } else {
                int kk = idx >> 5, n = idx & 31;
                Bs[kk][n] = Bm[(long long)(k0 + kk) * ldb + (n0 + n)];
            }
        }
        __syncthreads();
        #pragma unroll
        for (int kk = 0; kk < 32; ++kk) {
            float a0 = As[ty][kk];
            float a1 = As[ty + 16][kk];
            float b0 = Bs[kk][tx];
            float b1 = Bs[kk][tx + 16];
            acc00 += a0 * b0; acc01 += a0 * b1;
            acc10 += a1 * b0; acc11 += a1 * b1;
        }
        __syncthreads();
    }

    long long r0 = (long long)(m0 + ty) * ldc + n0;
    long long r1 = (long long)(m0 + ty + 16) * ldc + n0;
    if (ACC) {
        C[r0 + tx]      += acc00;
        C[r0 + tx + 16] += acc01;
        C[r1 + tx]      += acc10;
        C[r1 + tx + 16] += acc11;
    } else {
        C[r0 + tx]      = acc00;
        C[r0 + tx + 16] = acc01;
        C[r1 + tx]      = acc10;
        C[r1 + tx + 16] = acc11;
    }
}

// fp32 -> bf16 vectorized copy (n4 = number of float4 groups)
__global__ __launch_bounds__(256) void f2b_kernel(const float* __restrict__ in,
                                                  u16* __restrict__ out, long long n4)
{
    long long i = (long long)blockIdx.x * 256 + threadIdx.x;
    if (i >= n4) return;
    float4 v = ((const float4*)in)[i];
    u16x4 o = { f2b(v.x), f2b(v.y), f2b(v.z), f2b(v.w) };
    ((u16x4*)out)[i] = o;
}

// RMS norm rows of 768: fp32 in -> bf16 out (times weight)
__global__ __launch_bounds__(256) void rms_kernel(const float* __restrict__ qd,
                                                  const float* __restrict__ w,
                                                  u16* __restrict__ outb)
{
    const int row = blockIdx.x;
    const float* p = qd + (long long)row * Q_RANK;
    u16* ob = outb + (long long)row * Q_RANK;
    __shared__ float red[256];
    float s = 0.f;
    for (int i = threadIdx.x; i < Q_RANK; i += 256) { float v = p[i]; s += v * v; }
    red[threadIdx.x] = s;
    __syncthreads();
    for (int off = 128; off > 0; off >>= 1) {
        if (threadIdx.x < off) red[threadIdx.x] += red[threadIdx.x + off];
        __syncthreads();
    }
    float scale = rsqrtf(red[0] / (float)Q_RANK + RMS_EPS);
    for (int i = threadIdx.x; i < Q_RANK; i += 256) ob[i] = f2b(p[i] * scale * w[i]);
}

// Write new kv_latent + roped k_rope rows into the fp32 input caches.
__global__ __launch_bounds__(256) void cache_update(const float* __restrict__ kv,
                                                    const float* __restrict__ fc,
                                                    const float* __restrict__ fs,
                                                    float* __restrict__ kvc,
                                                    float* __restrict__ krc)
{
    const int bl = blockIdx.x;            // 0..255
    const int b = bl >> 5, l = bl & 31;
    const float* row = kv + (long long)bl * (KV_RANK + D_R);
    const int t = STARTP + l;
    float* dst = kvc + ((long long)b * MAX_T + t) * KV_RANK;
    for (int i = threadIdx.x; i < KV_RANK; i += 256) dst[i] = row[i];
    if (threadIdx.x < D_R / 2) {
        int i = threadIdx.x;
        float xr = row[KV_RANK + 2 * i];
        float xi = row[KV_RANK + 2 * i + 1];
        float c = fc[l * (D_R / 2) + i];
        float s = fs[l * (D_R / 2) + i];
        float* kd = krc + ((long long)b * MAX_T + t) * D_R;
        kd[2 * i]     = xr * c - xi * s;
        kd[2 * i + 1] = xr * s + xi * c;
    }
}

// roped q_rope -> qprime[b,h,l,512:576] (fp32)
__global__ __launch_bounds__(256) void rope_q(const float* __restrict__ q,
                                              const float* __restrict__ fc,
                                              const float* __restrict__ fs,
                                              float* __restrict__ qprime)
{
    int idx = blockIdx.x * 256 + threadIdx.x;   // 131072
    int i = idx & 31;
    int h = (idx >> 5) & (NH - 1);
    int l = (idx >> 9) & (NL - 1);
    int b = idx >> 14;
    const float* src = q + ((long long)(b * NL + l) * NH + h) * QK_DIM + D_NR + 2 * i;
    float xr = src[0], xi = src[1];
    float c = fc[l * (D_R / 2) + i];
    float s = fs[l * (D_R / 2) + i];
    float* dst = qprime + ((long long)(b * NH + h) * NL + l) * (KV_RANK + D_R) + KV_RANK + 2 * i;
    dst[0] = xr * c - xi * s;
    dst[1] = xr * s + xi * c;
}

// Transpose + convert latent cache: kvc fp32 (b,4096,512) -> kvcT bf16 (b,512,4096)
__global__ __launch_bounds__(256) void transpose_kvc(const float* __restrict__ kvc,
                                                     u16* __restrict__ kvcT)
{
    __shared__ u16 T[64][65];
    const int b = blockIdx.z;
    const int t0 = blockIdx.y * 64;
    const int k0 = blockIdx.x * 64;
    const int tid = threadIdx.x;
    const float* in = kvc + ((long long)b * MAX_T + t0) * KV_RANK + k0;
    #pragma unroll
    for (int i = 0; i < 16; ++i) {
        int lin = i * 256 + tid;
        int tr = lin >> 6, kc = lin & 63;
        T[kc][tr] = f2b(in[(long long)tr * KV_RANK + kc]);
    }
    __syncthreads();
    u16* outp = kvcT + ((long long)b * KV_RANK + k0) * MAX_T + t0;
    #pragma unroll
    for (int i = 0; i < 16; ++i) {
        int lin = i * 256 + tid;
        int kr = lin >> 6, tc = lin & 63;
        outp[(long long)kr * MAX_T + tc] = T[kr][tc];
    }
}

// Build bf16 concatenated B for scores: (b,4096,576) = [kvc | krc]
__global__ __launch_bounds__(256) void build_bcat(const float* __restrict__ kvc,
                                                  const float* __restrict__ krc,
                                                  u16* __restrict__ bcat)
{
    long long e = (long long)blockIdx.x * 256 + threadIdx.x;  // float4 groups
    if (e >= (long long)NB * MAX_T * 144) return;
    int c4 = (int)(e % 144);
    long long row = e / 144;                  // b*4096 + t
    int b = (int)(row >> 12); int t = (int)(row & 4095);
    float4 v;
    if (c4 < 128) v = ((const float4*)(kvc + ((long long)b * MAX_T + t) * KV_RANK))[c4];
    else          v = ((const float4*)(krc + ((long long)b * MAX_T + t) * D_R))[c4 - 128];
    u16x4 o = { f2b(v.x), f2b(v.y), f2b(v.z), f2b(v.w) };
    ((u16x4*)(bcat + row * (KV_RANK + D_R)))[c4] = o;
}

// Softmax: fp32 scores in, normalized bf16 P written in-place (row stride stays
// 4096 floats => 8192 u16). Masked tail = 0.
__global__ __launch_bounds__(256) void softmax_bf16(float* __restrict__ scores)
{
    const int row = blockIdx.x;     // b*512 + h*32 + l
    const int l = row & 31;
    const int vlen = STARTP + l + 1;
    float* s = scores + (long long)row * MAX_T;
    __shared__ float red[256];
    const int tid = threadIdx.x;

    float4 v[4];
    float m = -1e30f;
    #pragma unroll
    for (int i = 0; i < 4; ++i) {
        int f4 = i * 256 + tid;
        v[i] = ((const float4*)s)[f4];
        int t = f4 * 4;
        if (t + 0 >= vlen) v[i].x = -1e30f;
        if (t + 1 >= vlen) v[i].y = -1e30f;
        if (t + 2 >= vlen) v[i].z = -1e30f;
        if (t + 3 >= vlen) v[i].w = -1e30f;
        m = fmaxf(m, fmaxf(fmaxf(v[i].x, v[i].y), fmaxf(v[i].z, v[i].w)));
    }
    red[tid] = m; __syncthreads();
    for (int off = 128; off > 0; off >>= 1) {
        if (tid < off) red[tid] = fmaxf(red[tid], red[tid + off]);
        __syncthreads();
    }
    const float mm = red[0] * ATT_SCALE;
    __syncthreads();

    float sum = 0.f;
    #pragma unroll
    for (int i = 0; i < 4; ++i) {
        v[i].x = __expf(v[i].x * ATT_SCALE - mm);
        v[i].y = __expf(v[i].y * ATT_SCALE - mm);
        v[i].z = __expf(v[i].z * ATT_SCALE - mm);
        v[i].w = __expf(v[i].w * ATT_SCALE - mm);
        sum += v[i].x + v[i].y + v[i].z + v[i].w;
    }
    red[tid] = sum; __syncthreads();
    for (int off = 128; off > 0; off >>= 1) {
        if (tid < off) red[tid] += red[tid + off];
        __syncthreads();
    }
    const float inv = 1.0f / red[0];
    u16* ps = (u16*)s;
    #pragma unroll
    for (int i = 0; i < 4; ++i) {
        int f4 = i * 256 + tid;
        u16x4 o = { f2b(v[i].x * inv), f2b(v[i].y * inv), f2b(v[i].z * inv), f2b(v[i].w * inv) };
        ((u16x4*)ps)[f4] = o;
    }
}

extern "C" void kernel_launch(void* const* d_in, const int* in_sizes, int n_in,
                              void* d_out, int out_size, void* d_ws, size_t ws_size,
                              hipStream_t stream)
{
    const float* x        = (const float*)d_in[0];
    const float* fc       = (const float*)d_in[2];
    const float* fs       = (const float*)d_in[3];
    float* kvc            = (float*)d_in[5];
    float* krc            = (float*)d_in[6];
    const float* w_kv_down= (const float*)d_in[7];
    const float* w_q_down = (const float*)d_in[8];
    const float* rms_q_w  = (const float*)d_in[9];
    const float* w_q_up   = (const float*)d_in[10];
    const float* w_kv_up  = (const float*)d_in[11];
    const float* w_out    = (const float*)d_in[12];
    float* out            = (float*)d_out;

    // ---- workspace layout (fp32 region then bf16 region; ~177 MB) ----
    float* ws_f   = (float*)d_ws;
    float* q_down = ws_f;                       // 196608
    float* q      = q_down + 196608;            // 786432
    float* kv     = q + 786432;                 // 147456
    float* qprime = kv + 147456;                // 2359296
    float* scores = qprime + 2359296;           // 16777216 (later holds bf16 P in-place)
    u16* xb      = (u16*)(scores + 16777216);   // 524288
    u16* qdb     = xb + 524288;                 // 196608
    u16* qprimeb = qdb + 196608;                // 2359296
    u16* wqd_b   = qprimeb + 2359296;           // 1572864
    u16* wqu_b   = wqd_b + 1572864;             // 2359296
    u16* wkvd_b  = wqu_b + 2359296;             // 1179648
    u16* wout_b  = wkvd_b + 1179648;            // 4194304
    u16* kvcT    = wout_b + 4194304;            // 16777216
    u16* bcat    = kvcT + 16777216;             // 18874368
    // bcat dead after scores GEMM; reuse its region:
    float* o_heads = (float*)bcat;              // 4194304 floats
    float* o_up    = o_heads + 4194304;         // 524288 floats
    u16*   o_upb   = (u16*)(o_up + 524288);     // 524288 u16

    // ---- conversions ----
    f2b_kernel<<<131072 / 256, 256, 0, stream>>>(x, xb, 131072);
    f2b_kernel<<<393216 / 256, 256, 0, stream>>>(w_q_down, wqd_b, 393216);
    f2b_kernel<<<589824 / 256, 256, 0, stream>>>(w_q_up, wqu_b, 589824);
    f2b_kernel<<<294912 / 256, 256, 0, stream>>>(w_kv_down, wkvd_b, 294912);
    f2b_kernel<<<1048576 / 256, 256, 0, stream>>>(w_out, wout_b, 1048576);

    // 1) q_down = x @ w_q_down^T   (256,768,2048)
    gemm_mfma<64,64,2,2><<<dim3(12, 4, 1), 256, 0, stream>>>(
        xb, wqd_b, q_down, 2048, 2048, 2048, 768, 0, 0, 0);
    // 2) RMS -> bf16
    rms_kernel<<<256, 256, 0, stream>>>(q_down, rms_q_w, qdb);
    // 3) q = qn @ w_q_up^T         (256,3072,768)
    gemm_mfma<64,64,2,2><<<dim3(48, 4, 1), 256, 0, stream>>>(
        qdb, wqu_b, q, 768, 768, 768, 3072, 0, 0, 0);
    // 4) kv = x @ w_kv_down^T      (256,576,2048)
    gemm_mfma<64,64,2,2><<<dim3(9, 4, 1), 256, 0, stream>>>(
        xb, wkvd_b, kv, 2048, 2048, 2048, 576, 0, 0, 0);
    // 5) cache update (fp32, in place on inputs)
    cache_update<<<256, 256, 0, stream>>>(kv, fc, fs, kvc, krc);
    // 6) bf16 transposed latent cache + concatenated [kvc|krc]
    transpose_kvc<<<dim3(8, 64, 8), 256, 0, stream>>>(kvc, kvcT);
    build_bcat<<<18432, 256, 0, stream>>>(kvc, krc, bcat);
    // 7) q_abs per (b,h) (fp32) -> qprime[...,0:512]; rope -> [512:576]
    gemm32<false, false><<<dim3(16, 1, NB * NH), 256, 0, stream>>>(
        q, w_kv_up, qprime, 32, 512, 128, 3072, 512, 576,
        (long long)32 * 3072, 192, 0, (long long)256 * 512,
        (long long)NH * NL * 576, (long long)NL * 576, NH);
    rope_q<<<512, 256, 0, stream>>>(q, fc, fs, qprime);
    f2b_kernel<<<589824 / 256, 256, 0, stream>>>(qprime, qprimeb, 589824);
    // 8+9) scores = qprime @ [kvc|krc]^T per b  (512,4096,576)
    gemm_mfma<128,128,4,4><<<dim3(32, 4, NB), 256, 0, stream>>>(
        qprimeb, bcat, scores, 576, 576, 576, 4096,
        294912LL, 2359296LL, 2097152LL);
    // 10) softmax -> bf16 P in place
    softmax_bf16<<<NB * NH * NL, 256, 0, stream>>>(scores);
    // 11) o_heads = P @ kvcT^T per b   (512,512,4096)
    gemm_mfma<64,64,2,2><<<dim3(8, 8, NB), 256, 0, stream>>>(
        (const u16*)scores, kvcT, o_heads, 4096, 8192, 4096, 512,
        4194304LL, 2097152LL, 262144LL);
    // 12) o_up per (b,h) (fp32)
    gemm32<true, false><<<dim3(4, 1, NB * NH), 256, 0, stream>>>(
        o_heads, w_kv_up + 128 * 512, o_up, 32, 128, 512, 512, 512, 2048,
        (long long)NH * NL * 512, (long long)NL * 512, 0, (long long)256 * 512,
        (long long)NL * 2048, 128, NH);
    f2b_kernel<<<131072 / 256, 256, 0, stream>>>(o_up, o_upb, 131072);
    // 13) out = o_up @ w_out^T     (256,2048,2048)
    gemm_mfma<64,64,2,2><<<dim3(32, 4, 1), 256, 0, stream>>>(
        o_upb, wout_b, out, 2048, 2048, 2048, 2048, 0, 0, 0);
}

// Round 3
// 404.896 us; speedup vs baseline: 4.1062x; 1.1200x over previous
//
#include <hip/hip_runtime.h>
#include <math.h>

#define DIMX 2048
#define KV_RANK 512
#define Q_RANK 768
#define NH 16
#define D_NR 128
#define D_R 64
#define D_V 128
#define NB 8
#define NL 32
#define MAX_T 4096
#define STARTP (MAX_T - NL)      /* 4064 */
#define QK_DIM (D_NR + D_R)      /* 192 */
#define ATT_SCALE 0.07216878364870323f  /* 1/sqrt(192) */
#define RMS_EPS 1.1920929e-07f

typedef unsigned short u16;
typedef __attribute__((ext_vector_type(4))) unsigned short u16x4;
typedef __attribute__((ext_vector_type(8))) short short8;
typedef __attribute__((ext_vector_type(4))) float f32x4;

#define GLOBAL_AS __attribute__((address_space(1)))
#define LDS_AS __attribute__((address_space(3)))

__device__ inline u16 f2b(float f) {
    union { float f; unsigned u; } v; v.f = f;
    unsigned r = (v.u + 0x7fffu + ((v.u >> 16) & 1u)) >> 16;
    return (u16)r;
}
__device__ inline float b2f(u16 u) {
    union { unsigned u; float f; } v; v.u = ((unsigned)u) << 16; return v.f;
}

// ---------------------------------------------------------------------------
// bf16 MFMA GEMM, C = A * B^T (A (M,K), B (N,K), both row-major bf16), fp32 acc.
// BM x BN tile, 4 waves (2x2), MFR=BM/32, NFR=BN/32 16x16 fragments per wave.
// OUTB: store C as bf16 (else fp32). BSWZ: XCD swizzle, requires gridDim.z==8.
// Two-level batch: z1 = z/nb2, z2 = z%nb2.
// ---------------------------------------------------------------------------
template<int BM, int BN, bool OUTB, bool BSWZ>
__global__ __launch_bounds__(256) void gemm_mfma(
    const u16* __restrict__ A, const u16* __restrict__ B, void* __restrict__ Cv,
    int K, int lda, int ldb, int ldc,
    long long sA1, long long sA2, long long sB1, long long sB2,
    long long sC1, long long sC2, int nb2)
{
    constexpr int MFR = BM / 32;
    constexpr int NFR = BN / 32;
    int bx = blockIdx.x, by = blockIdx.y, bz = blockIdx.z;
    if (BSWZ) {
        int flat = bx + gridDim.x * (by + gridDim.y * bz);
        bz = flat & 7;
        int r = flat >> 3;
        bx = r % gridDim.x;
        by = r / gridDim.x;
    }
    const int z1 = bz / nb2, z2 = bz % nb2;
    A += z1 * sA1 + z2 * sA2;
    B += z1 * sB1 + z2 * sB2;

    const int m0 = by * BM;
    const int n0 = bx * BN;
    const int tid = threadIdx.x;
    const int lane = tid & 63;
    const int wid = tid >> 6;
    const int wm = wid >> 1, wn = wid & 1;
    const int l15 = lane & 15;
    const int l4  = lane >> 4;

    __shared__ __align__(16) u16 As[BM * 32];
    __shared__ __align__(16) u16 Bs[BN * 32];

    f32x4 acc[MFR][NFR];
    #pragma unroll
    for (int i = 0; i < MFR; ++i)
        #pragma unroll
        for (int j = 0; j < NFR; ++j)
            acc[i][j] = (f32x4)0.0f;

    constexpr int nA = BM / 16;   // wave-loads for A per K-step
    constexpr int nB = BN / 16;

    for (int k0 = 0; k0 < K; k0 += 32) {
        #pragma unroll
        for (int j = 0; j < nA / 4 + 1; ++j) {
            int jj = wid + j * 4;
            if (jj < nA) {
                int c = jj * 64 + lane;
                const u16* src = A + (long long)(m0 + (c >> 2)) * lda + k0 + (c & 3) * 8;
                u16* dst = &As[jj * 512];
                __builtin_amdgcn_global_load_lds((const GLOBAL_AS void*)src,
                                                 (LDS_AS void*)dst, 16, 0, 0);
            }
        }
        #pragma unroll
        for (int j = 0; j < nB / 4 + 1; ++j) {
            int jj = wid + j * 4;
            if (jj < nB) {
                int c = jj * 64 + lane;
                const u16* src = B + (long long)(n0 + (c >> 2)) * ldb + k0 + (c & 3) * 8;
                u16* dst = &Bs[jj * 512];
                __builtin_amdgcn_global_load_lds((const GLOBAL_AS void*)src,
                                                 (LDS_AS void*)dst, 16, 0, 0);
            }
        }
        __syncthreads();

        short8 a[MFR], b[NFR];
        #pragma unroll
        for (int mf = 0; mf < MFR; ++mf)
            a[mf] = *(const short8*)&As[(wm * 16 * MFR + mf * 16 + l15) * 32 + l4 * 8];
        #pragma unroll
        for (int nf = 0; nf < NFR; ++nf)
            b[nf] = *(const short8*)&Bs[(wn * 16 * NFR + nf * 16 + l15) * 32 + l4 * 8];
        #pragma unroll
        for (int mf = 0; mf < MFR; ++mf)
            #pragma unroll
            for (int nf = 0; nf < NFR; ++nf)
                acc[mf][nf] = __builtin_amdgcn_mfma_f32_16x16x32_bf16(
                    a[mf], b[nf], acc[mf][nf], 0, 0, 0);
        __syncthreads();
    }

    if (OUTB) {
        u16* C = (u16*)Cv + z1 * sC1 + z2 * sC2;
        #pragma unroll
        for (int mf = 0; mf < MFR; ++mf)
            #pragma unroll
            for (int nf = 0; nf < NFR; ++nf) {
                int r0 = m0 + wm * 16 * MFR + mf * 16 + l4 * 4;
                int c0 = n0 + wn * 16 * NFR + nf * 16 + l15;
                #pragma unroll
                for (int r = 0; r < 4; ++r)
                    C[(long long)(r0 + r) * ldc + c0] = f2b(acc[mf][nf][r]);
            }
    } else {
        float* C = (float*)Cv + z1 * sC1 + z2 * sC2;
        #pragma unroll
        for (int mf = 0; mf < MFR; ++mf)
            #pragma unroll
            for (int nf = 0; nf < NFR; ++nf) {
                int r0 = m0 + wm * 16 * MFR + mf * 16 + l4 * 4;
                int c0 = n0 + wn * 16 * NFR + nf * 16 + l15;
                #pragma unroll
                for (int r = 0; r < 4; ++r)
                    C[(long long)(r0 + r) * ldc + c0] = acc[mf][nf][r];
            }
    }
}

// ---------------------------------------------------------------------------
// One-shot fp32 -> bf16 conversions for 6 buffers (2D grid, y = segment).
// ---------------------------------------------------------------------------
struct Segs {
    const float* src[6];
    u16* dst[6];
    int n4[6];
};
__global__ __launch_bounds__(256) void f2b_multi(Segs s)
{
    int seg = blockIdx.y;
    int i = blockIdx.x * 256 + threadIdx.x;
    if (i >= s.n4[seg]) return;
    float4 v = ((const float4*)s.src[seg])[i];
    u16x4 o = { f2b(v.x), f2b(v.y), f2b(v.z), f2b(v.w) };
    ((u16x4*)s.dst[seg])[i] = o;
}

// RMS norm rows of 768: fp32 in -> bf16 out (times weight)
__global__ __launch_bounds__(256) void rms_kernel(const float* __restrict__ qd,
                                                  const float* __restrict__ w,
                                                  u16* __restrict__ outb)
{
    const int row = blockIdx.x;
    const float* p = qd + (long long)row * Q_RANK;
    u16* ob = outb + (long long)row * Q_RANK;
    __shared__ float red[256];
    float s = 0.f;
    for (int i = threadIdx.x; i < Q_RANK; i += 256) { float v = p[i]; s += v * v; }
    red[threadIdx.x] = s;
    __syncthreads();
    for (int off = 128; off > 0; off >>= 1) {
        if (threadIdx.x < off) red[threadIdx.x] += red[threadIdx.x + off];
        __syncthreads();
    }
    float scale = rsqrtf(red[0] / (float)Q_RANK + RMS_EPS);
    for (int i = threadIdx.x; i < Q_RANK; i += 256) ob[i] = f2b(p[i] * scale * w[i]);
}

// Transpose w_kv_up[:, :128] per head: fp32 (h,128,512) -> bf16 wuT (h,512,128)
__global__ __launch_bounds__(256) void wuT_kernel(const float* __restrict__ w,
                                                  u16* __restrict__ outp)
{
    __shared__ u16 T[64][65];
    const int h = blockIdx.z;
    const int y0 = blockIdx.y * 64;   // d-rows (0..127)
    const int x0 = blockIdx.x * 64;   // k-cols (0..511)
    const int tid = threadIdx.x;
    #pragma unroll
    for (int i = 0; i < 16; ++i) {
        int lin = i * 256 + tid;
        int r = lin >> 6, c = lin & 63;
        T[c][r] = f2b(w[((long long)h * 256 + y0 + r) * 512 + x0 + c]);
    }
    __syncthreads();
    #pragma unroll
    for (int i = 0; i < 16; ++i) {
        int lin = i * 256 + tid;
        int r = lin >> 6, c = lin & 63;
        outp[((long long)h * 512 + x0 + r) * 128 + y0 + c] = T[r][c];
    }
}

// bcat history rows (t < 4064): fp32 caches -> bf16 [kvc | krc]
__global__ __launch_bounds__(256) void bcat_hist(const float* __restrict__ kvc,
                                                 const float* __restrict__ krc,
                                                 u16* __restrict__ bcat)
{
    int e = blockIdx.x * 256 + threadIdx.x;
    if (e >= NB * STARTP * 144) return;
    int c4 = e % 144;
    int row = e / 144;                 // b*4064 + t
    int b = row / STARTP, t = row % STARTP;
    float4 v;
    if (c4 < 128) v = ((const float4*)(kvc + ((long long)b * MAX_T + t) * KV_RANK))[c4];
    else          v = ((const float4*)(krc + ((long long)b * MAX_T + t) * D_R))[c4 - 128];
    u16x4 o = { f2b(v.x), f2b(v.y), f2b(v.z), f2b(v.w) };
    ((u16x4*)(bcat + ((long long)b * MAX_T + t) * 576))[c4] = o;
}

// bcat new rows (t >= 4064): from bf16 kv (latent copy + rope on k_rope part)
__global__ __launch_bounds__(256) void bcat_new(const u16* __restrict__ kvb,
                                                const float* __restrict__ fc,
                                                const float* __restrict__ fs,
                                                u16* __restrict__ bcat)
{
    const int bl = blockIdx.x;        // 0..255
    const int b = bl >> 5, l = bl & 31;
    const u16* row = kvb + (long long)bl * 576;
    u16* dst = bcat + ((long long)b * MAX_T + STARTP + l) * 576;
    const int tid = threadIdx.x;
    if (tid < 128) {
        ((u16x4*)dst)[tid] = ((const u16x4*)row)[tid];
    } else if (tid < 160) {
        int i = tid - 128;
        float xr = b2f(row[512 + 2 * i]);
        float xi = b2f(row[512 + 2 * i + 1]);
        float c = fc[l * 32 + i], s = fs[l * 32 + i];
        dst[512 + 2 * i]     = f2b(xr * c - xi * s);
        dst[512 + 2 * i + 1] = f2b(xr * s + xi * c);
    }
}

// Transpose latent part of bcat: bf16 (b,4096,576)[:, :512] -> kvcT (b,512,4096)
__global__ __launch_bounds__(256) void t_kvcT(const u16* __restrict__ bcat,
                                              u16* __restrict__ kvcT)
{
    __shared__ u16 T[64][65];
    const int b = blockIdx.z;
    const int t0 = blockIdx.y * 64;   // 0..4095
    const int k0 = blockIdx.x * 64;   // 0..511
    const int tid = threadIdx.x;
    const u16* in = bcat + ((long long)b * MAX_T + t0) * 576 + k0;
    #pragma unroll
    for (int i = 0; i < 16; ++i) {
        int lin = i * 256 + tid;
        int r = lin >> 6, c = lin & 63;   // r = t, c = k
        T[c][r] = in[(long long)r * 576 + c];
    }
    __syncthreads();
    u16* outp = kvcT + ((long long)b * KV_RANK + k0) * MAX_T + t0;
    #pragma unroll
    for (int i = 0; i < 16; ++i) {
        int lin = i * 256 + tid;
        int r = lin >> 6, c = lin & 63;   // r = k, c = t
        outp[(long long)r * MAX_T + c] = T[r][c];
    }
}

// roped q_rope (bf16 q in) -> qprimeb[b,h,l,512:576] (bf16)
__global__ __launch_bounds__(256) void rope_q(const u16* __restrict__ qb,
                                              const float* __restrict__ fc,
                                              const float* __restrict__ fs,
                                              u16* __restrict__ qprimeb)
{
    int idx = blockIdx.x * 256 + threadIdx.x;   // 131072
    int i = idx & 31;
    int h = (idx >> 5) & (NH - 1);
    int l = (idx >> 9) & (NL - 1);
    int b = idx >> 14;
    const u16* src = qb + (long long)(b * NL + l) * 3072 + h * QK_DIM + D_NR + 2 * i;
    float xr = b2f(src[0]), xi = b2f(src[1]);
    float c = fc[l * 32 + i], s = fs[l * 32 + i];
    u16* dst = qprimeb + ((long long)(b * NH + h) * NL + l) * 576 + 512 + 2 * i;
    dst[0] = f2b(xr * c - xi * s);
    dst[1] = f2b(xr * s + xi * c);
}

// Softmax: fp32 scores in, normalized bf16 P written in-place. Masked tail = 0.
__global__ __launch_bounds__(256) void softmax_bf16(float* __restrict__ scores)
{
    const int row = blockIdx.x;     // b*512 + h*32 + l
    const int l = row & 31;
    const int vlen = STARTP + l + 1;
    float* s = scores + (long long)row * MAX_T;
    __shared__ float red[256];
    const int tid = threadIdx.x;

    float4 v[4];
    float m = -1e30f;
    #pragma unroll
    for (int i = 0; i < 4; ++i) {
        int f4 = i * 256 + tid;
        v[i] = ((const float4*)s)[f4];
        int t = f4 * 4;
        if (t + 0 >= vlen) v[i].x = -1e30f;
        if (t + 1 >= vlen) v[i].y = -1e30f;
        if (t + 2 >= vlen) v[i].z = -1e30f;
        if (t + 3 >= vlen) v[i].w = -1e30f;
        m = fmaxf(m, fmaxf(fmaxf(v[i].x, v[i].y), fmaxf(v[i].z, v[i].w)));
    }
    red[tid] = m; __syncthreads();
    for (int off = 128; off > 0; off >>= 1) {
        if (tid < off) red[tid] = fmaxf(red[tid], red[tid + off]);
        __syncthreads();
    }
    const float mm = red[0] * ATT_SCALE;
    __syncthreads();

    float sum = 0.f;
    #pragma unroll
    for (int i = 0; i < 4; ++i) {
        v[i].x = __expf(v[i].x * ATT_SCALE - mm);
        v[i].y = __expf(v[i].y * ATT_SCALE - mm);
        v[i].z = __expf(v[i].z * ATT_SCALE - mm);
        v[i].w = __expf(v[i].w * ATT_SCALE - mm);
        sum += v[i].x + v[i].y + v[i].z + v[i].w;
    }
    red[tid] = sum; __syncthreads();
    for (int off = 128; off > 0; off >>= 1) {
        if (tid < off) red[tid] += red[tid + off];
        __syncthreads();
    }
    const float inv = 1.0f / red[0];
    u16* ps = (u16*)s;
    #pragma unroll
    for (int i = 0; i < 4; ++i) {
        int f4 = i * 256 + tid;
        u16x4 o = { f2b(v[i].x * inv), f2b(v[i].y * inv), f2b(v[i].z * inv), f2b(v[i].w * inv) };
        ((u16x4*)ps)[f4] = o;
    }
}

extern "C" void kernel_launch(void* const* d_in, const int* in_sizes, int n_in,
                              void* d_out, int out_size, void* d_ws, size_t ws_size,
                              hipStream_t stream)
{
    const float* x        = (const float*)d_in[0];
    const float* fc       = (const float*)d_in[2];
    const float* fs       = (const float*)d_in[3];
    const float* kvc      = (const float*)d_in[5];
    const float* krc      = (const float*)d_in[6];
    const float* w_kv_down= (const float*)d_in[7];
    const float* w_q_down = (const float*)d_in[8];
    const float* rms_q_w  = (const float*)d_in[9];
    const float* w_q_up   = (const float*)d_in[10];
    const float* w_kv_up  = (const float*)d_in[11];
    const float* w_out    = (const float*)d_in[12];
    float* out            = (float*)d_out;

    // ---- workspace layout ----
    float* q_down  = (float*)d_ws;               // 196608 f
    float* scores  = q_down + 196608;            // 16777216 f (holds bf16 P after softmax)
    u16* base      = (u16*)(scores + 16777216);
    u16* xb      = base;                 base += 524288;    // 256x2048
    u16* qdb     = base;                 base += 196608;    // 256x768
    u16* qb      = base;                 base += 786432;    // 256x3072
    u16* kvb     = base;                 base += 147456;    // 256x576
    u16* qprimeb = base;                 base += 2359296;   // (b,h,l,576)
    u16* wqd_b   = base;                 base += 1572864;   // 768x2048
    u16* wqu_b   = base;                 base += 2359296;   // 3072x768
    u16* wkvd_b  = base;                 base += 1179648;   // 576x2048
    u16* wkvu_b  = base;                 base += 2097152;   // 4096x512
    u16* wout_b  = base;                 base += 4194304;   // 2048x2048
    u16* wuT     = base;                 base += 1048576;   // (h,512,128)
    u16* bcat    = base;                 base += 18874368;  // (b,4096,576)
    u16* kvcT    = base;                 base += 16777216;  // (b,512,4096)
    u16* o_hb    = base;                 base += 2097152;   // (b,512,512)
    u16* o_upb   = base;                 base += 524288;    // 256x2048

    // 1) all fp32->bf16 conversions in one launch
    Segs segs;
    segs.src[0] = x;         segs.dst[0] = xb;     segs.n4[0] = 131072;
    segs.src[1] = w_q_down;  segs.dst[1] = wqd_b;  segs.n4[1] = 393216;
    segs.src[2] = w_q_up;    segs.dst[2] = wqu_b;  segs.n4[2] = 589824;
    segs.src[3] = w_kv_down; segs.dst[3] = wkvd_b; segs.n4[3] = 294912;
    segs.src[4] = w_kv_up;   segs.dst[4] = wkvu_b; segs.n4[4] = 524288;
    segs.src[5] = w_out;     segs.dst[5] = wout_b; segs.n4[5] = 1048576;
    f2b_multi<<<dim3(4096, 6), 256, 0, stream>>>(segs);

    // 2) wuT (bf16 transposed W_UK) + bcat history rows
    wuT_kernel<<<dim3(8, 2, 16), 256, 0, stream>>>(w_kv_up, wuT);
    bcat_hist<<<(NB * STARTP * 144 + 255) / 256, 256, 0, stream>>>(kvc, krc, bcat);

    // 3) q_down = x @ w_q_down^T   (256,768,2048) fp32 out
    gemm_mfma<32, 64, false, false><<<dim3(12, 8, 1), 256, 0, stream>>>(
        xb, wqd_b, q_down, 2048, 2048, 2048, 768, 0, 0, 0, 0, 0, 0, 1);
    // 4) RMS -> bf16
    rms_kernel<<<256, 256, 0, stream>>>(q_down, rms_q_w, qdb);
    // 5) q = qn @ w_q_up^T         (256,3072,768) bf16 out
    gemm_mfma<64, 64, true, false><<<dim3(48, 4, 1), 256, 0, stream>>>(
        qdb, wqu_b, qb, 768, 768, 768, 3072, 0, 0, 0, 0, 0, 0, 1);
    // 6) kv = x @ w_kv_down^T      (256,576,2048) bf16 out
    gemm_mfma<32, 64, true, false><<<dim3(9, 8, 1), 256, 0, stream>>>(
        xb, wkvd_b, kvb, 2048, 2048, 2048, 576, 0, 0, 0, 0, 0, 0, 1);
    // 7) bcat new rows; then kvcT transpose (bf16 -> bf16)
    bcat_new<<<256, 256, 0, stream>>>(kvb, fc, fs, bcat);
    t_kvcT<<<dim3(8, 64, 8), 256, 0, stream>>>(bcat, kvcT);

    // 8) q_abs per (b,h): (32,512,128) bf16 -> qprimeb[...,0:512]
    gemm_mfma<32, 128, true, false><<<dim3(4, 1, 128), 256, 0, stream>>>(
        qb, wuT, qprimeb, 128, 3072, 128, 576,
        98304LL, 192LL, 0LL, 65536LL, 294912LL, 18432LL, 16);
    // 9) roped q_rope -> qprimeb[...,512:576]
    rope_q<<<512, 256, 0, stream>>>(qb, fc, fs, qprimeb);

    // 10) scores = qprime @ bcat^T per b  (512,4096,576) fp32 out, XCD swizzle
    gemm_mfma<128, 128, false, true><<<dim3(32, 4, 8), 256, 0, stream>>>(
        qprimeb, bcat, scores, 576, 576, 576, 4096,
        294912LL, 0LL, 2359296LL, 0LL, 2097152LL, 0LL, 1);
    // 11) softmax -> bf16 P in place
    softmax_bf16<<<NB * NH * NL, 256, 0, stream>>>(scores);
    // 12) o_heads = P @ kvcT^T per b (512,512,4096) bf16 out, XCD swizzle
    gemm_mfma<128, 128, true, true><<<dim3(4, 4, 8), 256, 0, stream>>>(
        (const u16*)scores, kvcT, o_hb, 4096, 8192, 4096, 512,
        4194304LL, 0LL, 2097152LL, 0LL, 262144LL, 0LL, 1);

    // 13) o_up per (b,h): (32,128,512) bf16
    gemm_mfma<32, 128, true, false><<<dim3(1, 1, 128), 256, 0, stream>>>(
        o_hb, wkvu_b + 128 * 512, o_upb, 512, 512, 512, 2048,
        262144LL, 16384LL, 0LL, 131072LL, 65536LL, 128LL, 16);
    // 14) out = o_up @ w_out^T     (256,2048,2048) fp32 out
    gemm_mfma<64, 64, false, false><<<dim3(32, 4, 1), 256, 0, stream>>>(
        o_upb, wout_b, out, 2048, 2048, 2048, 2048, 0, 0, 0, 0, 0, 0, 1);
}

// Round 4
// 345.547 us; speedup vs baseline: 4.8114x; 1.1718x over previous
//
#include <hip/hip_runtime.h>
#include <math.h>

#define DIMX 2048
#define KV_RANK 512
#define Q_RANK 768
#define NH 16
#define D_NR 128
#define D_R 64
#define D_V 128
#define NB 8
#define NL 32
#define MAX_T 4096
#define STARTP (MAX_T - NL)      /* 4064 */
#define QK_DIM (D_NR + D_R)      /* 192 */
#define ATT_SCALE 0.07216878364870323f  /* 1/sqrt(192) */
#define RMS_EPS 1.1920929e-07f

typedef unsigned short u16;
typedef __attribute__((ext_vector_type(4))) unsigned short u16x4;
typedef __attribute__((ext_vector_type(8))) short short8;
typedef __attribute__((ext_vector_type(4))) float f32x4;

#define GLOBAL_AS __attribute__((address_space(1)))
#define LDS_AS __attribute__((address_space(3)))

__device__ inline u16 f2b(float f) {
    union { float f; unsigned u; } v; v.f = f;
    unsigned r = (v.u + 0x7fffu + ((v.u >> 16) & 1u)) >> 16;
    return (u16)r;
}
__device__ inline float b2f(u16 u) {
    union { unsigned u; float f; } v; v.u = ((unsigned)u) << 16; return v.f;
}

// ---------------------------------------------------------------------------
// bf16 MFMA GEMM, C = A * B^T (A (M,K), B (N,K), row-major bf16), fp32 acc.
// BM x BN tile, 4 waves (2x2). OUTB: bf16 C. BSWZ: XCD swizzle (gridDim.z==8).
// Two-level batch: z1 = z/nb2, z2 = z%nb2. Split-K = use z2 with K-offset
// strides (sA2=sB2=K_chunk) and per-chunk C offset (sC2), pass K = chunk.
// ---------------------------------------------------------------------------
template<int BM, int BN, bool OUTB, bool BSWZ>
__global__ __launch_bounds__(256) void gemm_mfma(
    const u16* __restrict__ A, const u16* __restrict__ B, void* __restrict__ Cv,
    int K, int lda, int ldb, int ldc,
    long long sA1, long long sA2, long long sB1, long long sB2,
    long long sC1, long long sC2, int nb2)
{
    constexpr int MFR = BM / 32;
    constexpr int NFR = BN / 32;
    int bx = blockIdx.x, by = blockIdx.y, bz = blockIdx.z;
    if (BSWZ) {
        int flat = bx + gridDim.x * (by + gridDim.y * bz);
        bz = flat & 7;
        int r = flat >> 3;
        bx = r % gridDim.x;
        by = r / gridDim.x;
    }
    const int z1 = bz / nb2, z2 = bz % nb2;
    A += z1 * sA1 + z2 * sA2;
    B += z1 * sB1 + z2 * sB2;

    const int m0 = by * BM;
    const int n0 = bx * BN;
    const int tid = threadIdx.x;
    const int lane = tid & 63;
    const int wid = tid >> 6;
    const int wm = wid >> 1, wn = wid & 1;
    const int l15 = lane & 15;
    const int l4  = lane >> 4;

    __shared__ __align__(16) u16 As[BM * 32];
    __shared__ __align__(16) u16 Bs[BN * 32];

    f32x4 acc[MFR][NFR];
    #pragma unroll
    for (int i = 0; i < MFR; ++i)
        #pragma unroll
        for (int j = 0; j < NFR; ++j)
            acc[i][j] = (f32x4)0.0f;

    constexpr int nA = BM / 16;
    constexpr int nB = BN / 16;

    for (int k0 = 0; k0 < K; k0 += 32) {
        #pragma unroll
        for (int j = 0; j < nA / 4 + 1; ++j) {
            int jj = wid + j * 4;
            if (jj < nA) {
                int c = jj * 64 + lane;
                const u16* src = A + (long long)(m0 + (c >> 2)) * lda + k0 + (c & 3) * 8;
                u16* dst = &As[jj * 512];
                __builtin_amdgcn_global_load_lds((const GLOBAL_AS void*)src,
                                                 (LDS_AS void*)dst, 16, 0, 0);
            }
        }
        #pragma unroll
        for (int j = 0; j < nB / 4 + 1; ++j) {
            int jj = wid + j * 4;
            if (jj < nB) {
                int c = jj * 64 + lane;
                const u16* src = B + (long long)(n0 + (c >> 2)) * ldb + k0 + (c & 3) * 8;
                u16* dst = &Bs[jj * 512];
                __builtin_amdgcn_global_load_lds((const GLOBAL_AS void*)src,
                                                 (LDS_AS void*)dst, 16, 0, 0);
            }
        }
        __syncthreads();

        short8 a[MFR], b[NFR];
        #pragma unroll
        for (int mf = 0; mf < MFR; ++mf)
            a[mf] = *(const short8*)&As[(wm * 16 * MFR + mf * 16 + l15) * 32 + l4 * 8];
        #pragma unroll
        for (int nf = 0; nf < NFR; ++nf)
            b[nf] = *(const short8*)&Bs[(wn * 16 * NFR + nf * 16 + l15) * 32 + l4 * 8];
        #pragma unroll
        for (int mf = 0; mf < MFR; ++mf)
            #pragma unroll
            for (int nf = 0; nf < NFR; ++nf)
                acc[mf][nf] = __builtin_amdgcn_mfma_f32_16x16x32_bf16(
                    a[mf], b[nf], acc[mf][nf], 0, 0, 0);
        __syncthreads();
    }

    if (OUTB) {
        u16* C = (u16*)Cv + z1 * sC1 + z2 * sC2;
        #pragma unroll
        for (int mf = 0; mf < MFR; ++mf)
            #pragma unroll
            for (int nf = 0; nf < NFR; ++nf) {
                int r0 = m0 + wm * 16 * MFR + mf * 16 + l4 * 4;
                int c0 = n0 + wn * 16 * NFR + nf * 16 + l15;
                #pragma unroll
                for (int r = 0; r < 4; ++r)
                    C[(long long)(r0 + r) * ldc + c0] = f2b(acc[mf][nf][r]);
            }
    } else {
        float* C = (float*)Cv + z1 * sC1 + z2 * sC2;
        #pragma unroll
        for (int mf = 0; mf < MFR; ++mf)
            #pragma unroll
            for (int nf = 0; nf < NFR; ++nf) {
                int r0 = m0 + wm * 16 * MFR + mf * 16 + l4 * 4;
                int c0 = n0 + wn * 16 * NFR + nf * 16 + l15;
                #pragma unroll
                for (int r = 0; r < 4; ++r)
                    C[(long long)(r0 + r) * ldc + c0] = acc[mf][nf][r];
            }
    }
}

// ---------------------------------------------------------------------------
struct Segs {
    const float* src[6];
    u16* dst[6];
    int n4[6];
};
__global__ __launch_bounds__(256) void f2b_multi(Segs s)
{
    int seg = blockIdx.y;
    int i = blockIdx.x * 256 + threadIdx.x;
    if (i >= s.n4[seg]) return;
    float4 v = ((const float4*)s.src[seg])[i];
    u16x4 o = { f2b(v.x), f2b(v.y), f2b(v.z), f2b(v.w) };
    ((u16x4*)s.dst[seg])[i] = o;
}

// Sum 4 split-K partials then RMS-norm rows of 768 -> bf16 (times weight).
__global__ __launch_bounds__(256) void rms_reduce(const float* __restrict__ part,
                                                  const float* __restrict__ w,
                                                  u16* __restrict__ outb)
{
    const int row = blockIdx.x;          // 0..255
    const int tid = threadIdx.x;
    __shared__ float red[256];
    float val[3];
    float s = 0.f;
    #pragma unroll
    for (int j = 0; j < 3; ++j) {
        int i = tid + j * 256;
        long long off = (long long)row * Q_RANK + i;
        float v = part[off] + part[196608 + off] + part[393216 + off] + part[589824 + off];
        val[j] = v;
        s += v * v;
    }
    red[tid] = s; __syncthreads();
    for (int off = 128; off > 0; off >>= 1) {
        if (tid < off) red[tid] += red[tid + off];
        __syncthreads();
    }
    float scale = rsqrtf(red[0] / (float)Q_RANK + RMS_EPS);
    u16* ob = outb + (long long)row * Q_RANK;
    #pragma unroll
    for (int j = 0; j < 3; ++j) {
        int i = tid + j * 256;
        ob[i] = f2b(val[j] * scale * w[i]);
    }
}

// Transpose w_kv_up[:, :128] per head: fp32 (h,128,512) -> bf16 wuT (h,512,128)
__global__ __launch_bounds__(256) void wuT_kernel(const float* __restrict__ w,
                                                  u16* __restrict__ outp)
{
    __shared__ u16 T[64][65];
    const int h = blockIdx.z;
    const int y0 = blockIdx.y * 64;
    const int x0 = blockIdx.x * 64;
    const int tid = threadIdx.x;
    #pragma unroll
    for (int i = 0; i < 16; ++i) {
        int lin = i * 256 + tid;
        int r = lin >> 6, c = lin & 63;
        T[c][r] = f2b(w[((long long)h * 256 + y0 + r) * 512 + x0 + c]);
    }
    __syncthreads();
    #pragma unroll
    for (int i = 0; i < 16; ++i) {
        int lin = i * 256 + tid;
        int r = lin >> 6, c = lin & 63;
        outp[((long long)h * 512 + x0 + r) * 128 + y0 + c] = T[r][c];
    }
}

// bcat history rows (t < 4064): fp32 caches -> bf16 [kvc | krc]
__global__ __launch_bounds__(256) void bcat_hist(const float* __restrict__ kvc,
                                                 const float* __restrict__ krc,
                                                 u16* __restrict__ bcat)
{
    int e = blockIdx.x * 256 + threadIdx.x;
    if (e >= NB * STARTP * 144) return;
    int c4 = e % 144;
    int row = e / 144;
    int b = row / STARTP, t = row % STARTP;
    float4 v;
    if (c4 < 128) v = ((const float4*)(kvc + ((long long)b * MAX_T + t) * KV_RANK))[c4];
    else          v = ((const float4*)(krc + ((long long)b * MAX_T + t) * D_R))[c4 - 128];
    u16x4 o = { f2b(v.x), f2b(v.y), f2b(v.z), f2b(v.w) };
    ((u16x4*)(bcat + ((long long)b * MAX_T + t) * 576))[c4] = o;
}

// Sum 4 kv split-K partials; write new bcat rows (latent + roped k_rope).
__global__ __launch_bounds__(256) void bcat_new_reduce(const float* __restrict__ part,
                                                       const float* __restrict__ fc,
                                                       const float* __restrict__ fs,
                                                       u16* __restrict__ bcat)
{
    const int bl = blockIdx.x;        // 0..255
    const int b = bl >> 5, l = bl & 31;
    const int t = threadIdx.x;
    if (t >= 144) return;
    long long off = (long long)bl * 576 + 4 * t;
    const float4* p0 = (const float4*)(part + off);
    float4 v0 = p0[0];
    float4 v1 = *(const float4*)(part + 147456 + off);
    float4 v2 = *(const float4*)(part + 294912 + off);
    float4 v3 = *(const float4*)(part + 442368 + off);
    float4 v = { v0.x + v1.x + v2.x + v3.x, v0.y + v1.y + v2.y + v3.y,
                 v0.z + v1.z + v2.z + v3.z, v0.w + v1.w + v2.w + v3.w };
    u16* dst = bcat + ((long long)b * MAX_T + STARTP + l) * 576;
    if (t < 128) {
        u16x4 o = { f2b(v.x), f2b(v.y), f2b(v.z), f2b(v.w) };
        ((u16x4*)dst)[t] = o;
    } else {
        int g = t - 128;                  // pair group: pairs 2g, 2g+1
        float c0 = fc[l * 32 + 2 * g],     s0 = fs[l * 32 + 2 * g];
        float c1 = fc[l * 32 + 2 * g + 1], s1 = fs[l * 32 + 2 * g + 1];
        u16x4 o = { f2b(v.x * c0 - v.y * s0), f2b(v.x * s0 + v.y * c0),
                    f2b(v.z * c1 - v.w * s1), f2b(v.z * s1 + v.w * c1) };
        *(u16x4*)(dst + 512 + 4 * g) = o;
    }
}

// Transpose latent part of bcat: bf16 (b,4096,576)[:, :512] -> kvcT (b,512,4096)
__global__ __launch_bounds__(256) void t_kvcT(const u16* __restrict__ bcat,
                                              u16* __restrict__ kvcT)
{
    __shared__ u16 T[64][65];
    const int b = blockIdx.z;
    const int t0 = blockIdx.y * 64;
    const int k0 = blockIdx.x * 64;
    const int tid = threadIdx.x;
    const u16* in = bcat + ((long long)b * MAX_T + t0) * 576 + k0;
    #pragma unroll
    for (int i = 0; i < 16; ++i) {
        int lin = i * 256 + tid;
        int r = lin >> 6, c = lin & 63;
        T[c][r] = in[(long long)r * 576 + c];
    }
    __syncthreads();
    u16* outp = kvcT + ((long long)b * KV_RANK + k0) * MAX_T + t0;
    #pragma unroll
    for (int i = 0; i < 16; ++i) {
        int lin = i * 256 + tid;
        int r = lin >> 6, c = lin & 63;
        outp[(long long)r * MAX_T + c] = T[r][c];
    }
}

// roped q_rope (bf16 q in) -> qprimeb[b,h,l,512:576]
__global__ __launch_bounds__(256) void rope_q(const u16* __restrict__ qb,
                                              const float* __restrict__ fc,
                                              const float* __restrict__ fs,
                                              u16* __restrict__ qprimeb)
{
    int idx = blockIdx.x * 256 + threadIdx.x;
    int i = idx & 31;
    int h = (idx >> 5) & (NH - 1);
    int l = (idx >> 9) & (NL - 1);
    int b = idx >> 14;
    const u16* src = qb + (long long)(b * NL + l) * 3072 + h * QK_DIM + D_NR + 2 * i;
    float xr = b2f(src[0]), xi = b2f(src[1]);
    float c = fc[l * 32 + i], s = fs[l * 32 + i];
    u16* dst = qprimeb + ((long long)(b * NH + h) * NL + l) * 576 + 512 + 2 * i;
    dst[0] = f2b(xr * c - xi * s);
    dst[1] = f2b(xr * s + xi * c);
}

// Softmax: fp32 scores in, normalized bf16 P in place. Masked tail = 0.
__global__ __launch_bounds__(256) void softmax_bf16(float* __restrict__ scores)
{
    const int row = blockIdx.x;
    const int l = row & 31;
    const int vlen = STARTP + l + 1;
    float* s = scores + (long long)row * MAX_T;
    __shared__ float red[256];
    const int tid = threadIdx.x;

    float4 v[4];
    float m = -1e30f;
    #pragma unroll
    for (int i = 0; i < 4; ++i) {
        int f4 = i * 256 + tid;
        v[i] = ((const float4*)s)[f4];
        int t = f4 * 4;
        if (t + 0 >= vlen) v[i].x = -1e30f;
        if (t + 1 >= vlen) v[i].y = -1e30f;
        if (t + 2 >= vlen) v[i].z = -1e30f;
        if (t + 3 >= vlen) v[i].w = -1e30f;
        m = fmaxf(m, fmaxf(fmaxf(v[i].x, v[i].y), fmaxf(v[i].z, v[i].w)));
    }
    red[tid] = m; __syncthreads();
    for (int off = 128; off > 0; off >>= 1) {
        if (tid < off) red[tid] = fmaxf(red[tid], red[tid + off]);
        __syncthreads();
    }
    const float mm = red[0] * ATT_SCALE;
    __syncthreads();

    float sum = 0.f;
    #pragma unroll
    for (int i = 0; i < 4; ++i) {
        v[i].x = __expf(v[i].x * ATT_SCALE - mm);
        v[i].y = __expf(v[i].y * ATT_SCALE - mm);
        v[i].z = __expf(v[i].z * ATT_SCALE - mm);
        v[i].w = __expf(v[i].w * ATT_SCALE - mm);
        sum += v[i].x + v[i].y + v[i].z + v[i].w;
    }
    red[tid] = sum; __syncthreads();
    for (int off = 128; off > 0; off >>= 1) {
        if (tid < off) red[tid] += red[tid + off];
        __syncthreads();
    }
    const float inv = 1.0f / red[0];
    u16* ps = (u16*)s;
    #pragma unroll
    for (int i = 0; i < 4; ++i) {
        int f4 = i * 256 + tid;
        u16x4 o = { f2b(v[i].x * inv), f2b(v[i].y * inv), f2b(v[i].z * inv), f2b(v[i].w * inv) };
        ((u16x4*)ps)[f4] = o;
    }
}

// Sum 4 PV split-K partials -> bf16 o_hb. 524288 float4 groups total.
__global__ __launch_bounds__(256) void reduce_pv(const float* __restrict__ part,
                                                 u16* __restrict__ o_hb)
{
    int idx = blockIdx.x * 256 + threadIdx.x;     // < 524288
    int b = idx >> 16;
    int i4 = idx & 65535;
    const float* p = part + (long long)b * 1048576 + 4 * i4;
    float4 v0 = *(const float4*)p;
    float4 v1 = *(const float4*)(p + 262144);
    float4 v2 = *(const float4*)(p + 524288);
    float4 v3 = *(const float4*)(p + 786432);
    u16x4 o = { f2b(v0.x + v1.x + v2.x + v3.x), f2b(v0.y + v1.y + v2.y + v3.y),
                f2b(v0.z + v1.z + v2.z + v3.z), f2b(v0.w + v1.w + v2.w + v3.w) };
    ((u16x4*)(o_hb + (long long)b * 262144))[i4] = o;
}

// Sum 4 out-proj split-K partials -> fp32 out. 131072 float4 groups.
__global__ __launch_bounds__(256) void reduce_out(const float* __restrict__ part,
                                                  float* __restrict__ out)
{
    int idx = blockIdx.x * 256 + threadIdx.x;     // < 131072
    const float* p = part + 4 * (long long)idx;
    float4 v0 = *(const float4*)p;
    float4 v1 = *(const float4*)(p + 524288);
    float4 v2 = *(const float4*)(p + 1048576);
    float4 v3 = *(const float4*)(p + 1572864);
    float4 o = { v0.x + v1.x + v2.x + v3.x, v0.y + v1.y + v2.y + v3.y,
                 v0.z + v1.z + v2.z + v3.z, v0.w + v1.w + v2.w + v3.w };
    ((float4*)out)[idx] = o;
}

extern "C" void kernel_launch(void* const* d_in, const int* in_sizes, int n_in,
                              void* d_out, int out_size, void* d_ws, size_t ws_size,
                              hipStream_t stream)
{
    const float* x        = (const float*)d_in[0];
    const float* fc       = (const float*)d_in[2];
    const float* fs       = (const float*)d_in[3];
    const float* kvc      = (const float*)d_in[5];
    const float* krc      = (const float*)d_in[6];
    const float* w_kv_down= (const float*)d_in[7];
    const float* w_q_down = (const float*)d_in[8];
    const float* rms_q_w  = (const float*)d_in[9];
    const float* w_q_up   = (const float*)d_in[10];
    const float* w_kv_up  = (const float*)d_in[11];
    const float* w_out    = (const float*)d_in[12];
    float* out            = (float*)d_out;

    // ---- workspace layout ----
    float* qd_part = (float*)d_ws;               // 4 x 256x768   = 786432 f
    float* kv_part = qd_part + 786432;           // 4 x 256x576   = 589824 f
    float* scores  = kv_part + 589824;           // 16777216 f (bf16 P after softmax)
    u16* base      = (u16*)(scores + 16777216);
    u16* xb      = base;                 base += 524288;    // 256x2048
    u16* qdb     = base;                 base += 196608;    // 256x768
    u16* qb      = base;                 base += 786432;    // 256x3072
    u16* qprimeb = base;                 base += 2359296;   // (b,h,l,576)
    u16* wqd_b   = base;                 base += 1572864;
    u16* wqu_b   = base;                 base += 2359296;
    u16* wkvd_b  = base;                 base += 1179648;
    u16* wkvu_b  = base;                 base += 2097152;
    u16* wout_b  = base;                 base += 4194304;
    u16* wuT     = base;                 base += 1048576;   // (h,512,128)
    u16* bcat    = base;                 base += 18874368;  // (b,4096,576)
    u16* kvcT    = base;                 base += 16777216;  // (b,512,4096)
    u16* o_hb    = base;                 base += 2097152;   // (b,512,512)
    u16* o_upb   = base;                 base += 524288;    // 256x2048
    // aliases over dead regions:
    float* pv_part  = (float*)bcat;   // 4x8x512x512 f = 8388608 f (32 MB <= 36 MB) after scores GEMM
    float* out_part = (float*)kvcT;   // 4x256x2048 f = 2097152 f (8 MB <= 32 MB) after PV

    // 1) fp32->bf16 conversions
    Segs segs;
    segs.src[0] = x;         segs.dst[0] = xb;     segs.n4[0] = 131072;
    segs.src[1] = w_q_down;  segs.dst[1] = wqd_b;  segs.n4[1] = 393216;
    segs.src[2] = w_q_up;    segs.dst[2] = wqu_b;  segs.n4[2] = 589824;
    segs.src[3] = w_kv_down; segs.dst[3] = wkvd_b; segs.n4[3] = 294912;
    segs.src[4] = w_kv_up;   segs.dst[4] = wkvu_b; segs.n4[4] = 524288;
    segs.src[5] = w_out;     segs.dst[5] = wout_b; segs.n4[5] = 1048576;
    f2b_multi<<<dim3(4096, 6), 256, 0, stream>>>(segs);

    wuT_kernel<<<dim3(8, 2, 16), 256, 0, stream>>>(w_kv_up, wuT);
    bcat_hist<<<(NB * STARTP * 144 + 255) / 256, 256, 0, stream>>>(kvc, krc, bcat);

    // 2) q_down split-K=4: (256,768,2048) -> qd_part
    gemm_mfma<32, 64, false, false><<<dim3(12, 8, 4), 256, 0, stream>>>(
        xb, wqd_b, qd_part, 512, 2048, 2048, 768,
        0LL, 512LL, 0LL, 512LL, 0LL, 196608LL, 4);
    // 3) reduce + RMS -> bf16
    rms_reduce<<<256, 256, 0, stream>>>(qd_part, rms_q_w, qdb);
    // 4) q = qn @ w_q_up^T  (256,3072,768) bf16
    gemm_mfma<32, 64, true, false><<<dim3(48, 8, 1), 256, 0, stream>>>(
        qdb, wqu_b, qb, 768, 768, 768, 3072, 0, 0, 0, 0, 0, 0, 1);
    // 5) kv split-K=4: (256,576,2048) -> kv_part
    gemm_mfma<32, 64, false, false><<<dim3(9, 8, 4), 256, 0, stream>>>(
        xb, wkvd_b, kv_part, 512, 2048, 2048, 576,
        0LL, 512LL, 0LL, 512LL, 0LL, 147456LL, 4);
    // 6) reduce + new bcat rows (latent + rope)
    bcat_new_reduce<<<256, 256, 0, stream>>>(kv_part, fc, fs, bcat);
    t_kvcT<<<dim3(8, 64, 8), 256, 0, stream>>>(bcat, kvcT);

    // 7) q_abs per (b,h) -> qprimeb[...,0:512]; rope -> [512:576]
    gemm_mfma<32, 128, true, false><<<dim3(4, 1, 128), 256, 0, stream>>>(
        qb, wuT, qprimeb, 128, 3072, 128, 576,
        98304LL, 192LL, 0LL, 65536LL, 294912LL, 18432LL, 16);
    rope_q<<<512, 256, 0, stream>>>(qb, fc, fs, qprimeb);

    // 8) scores = qprime @ bcat^T per b (512,4096,576), XCD swizzle
    gemm_mfma<128, 128, false, true><<<dim3(32, 4, 8), 256, 0, stream>>>(
        qprimeb, bcat, scores, 576, 576, 576, 4096,
        294912LL, 0LL, 2359296LL, 0LL, 2097152LL, 0LL, 1);
    // 9) softmax -> bf16 P in place
    softmax_bf16<<<NB * NH * NL, 256, 0, stream>>>(scores);
    // 10) PV split-K=4: (512,512,4096) per b -> pv_part
    gemm_mfma<128, 128, false, false><<<dim3(4, 4, 32), 256, 0, stream>>>(
        (const u16*)scores, kvcT, pv_part, 1024, 8192, 4096, 512,
        4194304LL, 1024LL, 2097152LL, 1024LL, 1048576LL, 262144LL, 4);
    // 11) reduce -> bf16 o_hb
    reduce_pv<<<2048, 256, 0, stream>>>(pv_part, o_hb);

    // 12) o_up per (b,h): (32,128,512) bf16
    gemm_mfma<32, 64, true, false><<<dim3(2, 1, 128), 256, 0, stream>>>(
        o_hb, wkvu_b + 128 * 512, o_upb, 512, 512, 512, 2048,
        262144LL, 16384LL, 0LL, 131072LL, 65536LL, 128LL, 16);
    // 13) out-proj split-K=4: (256,2048,2048) -> out_part, reduce -> out
    gemm_mfma<32, 64, false, false><<<dim3(32, 8, 4), 256, 0, stream>>>(
        o_upb, wout_b, out_part, 512, 2048, 2048, 2048,
        0LL, 512LL, 0LL, 512LL, 0LL, 524288LL, 4);
    reduce_out<<<512, 256, 0, stream>>>(out_part, out);
}

// Round 5
// 339.000 us; speedup vs baseline: 4.9044x; 1.0193x over previous
//
#include <hip/hip_runtime.h>
#include <math.h>

#define DIMX 2048
#define KV_RANK 512
#define Q_RANK 768
#define NH 16
#define D_NR 128
#define D_R 64
#define D_V 128
#define NB 8
#define NL 32
#define MAX_T 4096
#define STARTP (MAX_T - NL)      /* 4064 */
#define QK_DIM (D_NR + D_R)      /* 192 */
#define ATT_SCALE 0.07216878364870323f  /* 1/sqrt(192) */
#define RMS_EPS 1.1920929e-07f

typedef unsigned short u16;
typedef __attribute__((ext_vector_type(4))) unsigned short u16x4;
typedef __attribute__((ext_vector_type(8))) short short8;
typedef __attribute__((ext_vector_type(4))) float f32x4;

#define GLOBAL_AS __attribute__((address_space(1)))
#define LDS_AS __attribute__((address_space(3)))

#define NDOWN 1344                 /* 768 + 576 fused down-proj N */
#define DPART ((long long)256 * NDOWN)   /* per-split partial stride */

__device__ inline u16 f2b(float f) {
    union { float f; unsigned u; } v; v.f = f;
    unsigned r = (v.u + 0x7fffu + ((v.u >> 16) & 1u)) >> 16;
    return (u16)r;
}
__device__ inline float b2f(u16 u) {
    union { unsigned u; float f; } v; v.u = ((unsigned)u) << 16; return v.f;
}

// ---------------------------------------------------------------------------
// bf16 MFMA GEMM, C = A * B^T (A (M,K), B (N,K), row-major bf16), fp32 acc.
// BM x BN tile, 4 waves (2x2). OUTB: bf16 C. GSWZ: XCD-chunked swizzle
// (requires total workgroups % 8 == 0): each XCD processes a CONTIGUOUS
// logical block range so blocks sharing A/B panels share one L2.
// Two-level batch: z1 = z/nb2, z2 = z%nb2. Split-K via z2 K-offset strides.
// ---------------------------------------------------------------------------
template<int BM, int BN, bool OUTB, bool GSWZ>
__global__ __launch_bounds__(256) void gemm_mfma(
    const u16* __restrict__ A, const u16* __restrict__ B, void* __restrict__ Cv,
    int K, int lda, int ldb, int ldc,
    long long sA1, long long sA2, long long sB1, long long sB2,
    long long sC1, long long sC2, int nb2)
{
    constexpr int MFR = BM / 32;
    constexpr int NFR = BN / 32;
    int bx = blockIdx.x, by = blockIdx.y, bz = blockIdx.z;
    if (GSWZ) {
        int flat = bx + gridDim.x * (by + gridDim.y * bz);
        int nwg = gridDim.x * gridDim.y * gridDim.z;
        int lf = (flat & 7) * (nwg >> 3) + (flat >> 3);
        bx = lf % gridDim.x;
        int r = lf / gridDim.x;
        by = r % gridDim.y;
        bz = r / gridDim.y;
    }
    const int z1 = bz / nb2, z2 = bz % nb2;
    A += z1 * sA1 + z2 * sA2;
    B += z1 * sB1 + z2 * sB2;

    const int m0 = by * BM;
    const int n0 = bx * BN;
    const int tid = threadIdx.x;
    const int lane = tid & 63;
    const int wid = tid >> 6;
    const int wm = wid >> 1, wn = wid & 1;
    const int l15 = lane & 15;
    const int l4  = lane >> 4;

    __shared__ __align__(16) u16 As[BM * 32];
    __shared__ __align__(16) u16 Bs[BN * 32];

    f32x4 acc[MFR][NFR];
    #pragma unroll
    for (int i = 0; i < MFR; ++i)
        #pragma unroll
        for (int j = 0; j < NFR; ++j)
            acc[i][j] = (f32x4)0.0f;

    constexpr int nA = BM / 16;
    constexpr int nB = BN / 16;

    for (int k0 = 0; k0 < K; k0 += 32) {
        #pragma unroll
        for (int j = 0; j < nA / 4 + 1; ++j) {
            int jj = wid + j * 4;
            if (jj < nA) {
                int c = jj * 64 + lane;
                const u16* src = A + (long long)(m0 + (c >> 2)) * lda + k0 + (c & 3) * 8;
                u16* dst = &As[jj * 512];
                __builtin_amdgcn_global_load_lds((const GLOBAL_AS void*)src,
                                                 (LDS_AS void*)dst, 16, 0, 0);
            }
        }
        #pragma unroll
        for (int j = 0; j < nB / 4 + 1; ++j) {
            int jj = wid + j * 4;
            if (jj < nB) {
                int c = jj * 64 + lane;
                const u16* src = B + (long long)(n0 + (c >> 2)) * ldb + k0 + (c & 3) * 8;
                u16* dst = &Bs[jj * 512];
                __builtin_amdgcn_global_load_lds((const GLOBAL_AS void*)src,
                                                 (LDS_AS void*)dst, 16, 0, 0);
            }
        }
        __syncthreads();

        short8 a[MFR], b[NFR];
        #pragma unroll
        for (int mf = 0; mf < MFR; ++mf)
            a[mf] = *(const short8*)&As[(wm * 16 * MFR + mf * 16 + l15) * 32 + l4 * 8];
        #pragma unroll
        for (int nf = 0; nf < NFR; ++nf)
            b[nf] = *(const short8*)&Bs[(wn * 16 * NFR + nf * 16 + l15) * 32 + l4 * 8];
        #pragma unroll
        for (int mf = 0; mf < MFR; ++mf)
            #pragma unroll
            for (int nf = 0; nf < NFR; ++nf)
                acc[mf][nf] = __builtin_amdgcn_mfma_f32_16x16x32_bf16(
                    a[mf], b[nf], acc[mf][nf], 0, 0, 0);
        __syncthreads();
    }

    if (OUTB) {
        u16* C = (u16*)Cv + z1 * sC1 + z2 * sC2;
        #pragma unroll
        for (int mf = 0; mf < MFR; ++mf)
            #pragma unroll
            for (int nf = 0; nf < NFR; ++nf) {
                int r0 = m0 + wm * 16 * MFR + mf * 16 + l4 * 4;
                int c0 = n0 + wn * 16 * NFR + nf * 16 + l15;
                #pragma unroll
                for (int r = 0; r < 4; ++r)
                    C[(long long)(r0 + r) * ldc + c0] = f2b(acc[mf][nf][r]);
            }
    } else {
        float* C = (float*)Cv + z1 * sC1 + z2 * sC2;
        #pragma unroll
        for (int mf = 0; mf < MFR; ++mf)
            #pragma unroll
            for (int nf = 0; nf < NFR; ++nf) {
                int r0 = m0 + wm * 16 * MFR + mf * 16 + l4 * 4;
                int c0 = n0 + wn * 16 * NFR + nf * 16 + l15;
                #pragma unroll
                for (int r = 0; r < 4; ++r)
                    C[(long long)(r0 + r) * ldc + c0] = acc[mf][nf][r];
            }
    }
}

// ---------------------------------------------------------------------------
struct Segs {
    const float* src[6];
    u16* dst[6];
    int n4[6];
};
__global__ __launch_bounds__(256) void f2b_multi(Segs s)
{
    int seg = blockIdx.y;
    int i = blockIdx.x * 256 + threadIdx.x;
    if (i >= s.n4[seg]) return;
    float4 v = ((const float4*)s.src[seg])[i];
    u16x4 o = { f2b(v.x), f2b(v.y), f2b(v.z), f2b(v.w) };
    ((u16x4*)s.dst[seg])[i] = o;
}

// Sum 4 split-K partials (cols 0..767 of fused down output), RMS-norm -> bf16.
__global__ __launch_bounds__(256) void rms_reduce(const float* __restrict__ part,
                                                  const float* __restrict__ w,
                                                  u16* __restrict__ outb)
{
    const int row = blockIdx.x;          // 0..255
    const int tid = threadIdx.x;
    __shared__ float red[256];
    float val[3];
    float s = 0.f;
    #pragma unroll
    for (int j = 0; j < 3; ++j) {
        int i = tid + j * 256;
        long long off = (long long)row * NDOWN + i;
        float v = part[off] + part[DPART + off] + part[2 * DPART + off] + part[3 * DPART + off];
        val[j] = v;
        s += v * v;
    }
    red[tid] = s; __syncthreads();
    for (int off = 128; off > 0; off >>= 1) {
        if (tid < off) red[tid] += red[tid + off];
        __syncthreads();
    }
    float scale = rsqrtf(red[0] / (float)Q_RANK + RMS_EPS);
    u16* ob = outb + (long long)row * Q_RANK;
    #pragma unroll
    for (int j = 0; j < 3; ++j) {
        int i = tid + j * 256;
        ob[i] = f2b(val[j] * scale * w[i]);
    }
}

// Transpose w_kv_up[:, :128] per head: fp32 (h,128,512) -> bf16 wuT (h,512,128)
__global__ __launch_bounds__(256) void wuT_kernel(const float* __restrict__ w,
                                                  u16* __restrict__ outp)
{
    __shared__ u16 T[64][65];
    const int h = blockIdx.z;
    const int y0 = blockIdx.y * 64;
    const int x0 = blockIdx.x * 64;
    const int tid = threadIdx.x;
    #pragma unroll
    for (int i = 0; i < 16; ++i) {
        int lin = i * 256 + tid;
        int r = lin >> 6, c = lin & 63;
        T[c][r] = f2b(w[((long long)h * 256 + y0 + r) * 512 + x0 + c]);
    }
    __syncthreads();
    #pragma unroll
    for (int i = 0; i < 16; ++i) {
        int lin = i * 256 + tid;
        int r = lin >> 6, c = lin & 63;
        outp[((long long)h * 512 + x0 + r) * 128 + y0 + c] = T[r][c];
    }
}

// Copy roped history k_rope: fp32 krc -> bcat[:, :4064, 512:576] bf16
__global__ __launch_bounds__(256) void bcat_rope_hist(const float* __restrict__ krc,
                                                      u16* __restrict__ bcat)
{
    int e = blockIdx.x * 256 + threadIdx.x;      // < 8*4064*16
    if (e >= NB * STARTP * 16) return;
    int c4 = e & 15;
    int row = e >> 4;                  // b*4064 + t
    int b = row / STARTP, t = row - b * STARTP;
    float4 v = ((const float4*)(krc + ((long long)b * MAX_T + t) * D_R))[c4];
    u16x4 o = { f2b(v.x), f2b(v.y), f2b(v.z), f2b(v.w) };
    ((u16x4*)(bcat + ((long long)b * MAX_T + t) * 576 + 512))[c4] = o;
}

// Sum 4 kv split-K partials (cols 768.. of fused down output);
// write new bcat rows (latent + roped k_rope).
__global__ __launch_bounds__(256) void bcat_new_reduce(const float* __restrict__ part,
                                                       const float* __restrict__ fc,
                                                       const float* __restrict__ fs,
                                                       u16* __restrict__ bcat)
{
    const int bl = blockIdx.x;        // 0..255
    const int b = bl >> 5, l = bl & 31;
    const int t = threadIdx.x;
    if (t >= 144) return;
    long long off = (long long)bl * NDOWN + 768 + 4 * t;
    float4 v0 = *(const float4*)(part + off);
    float4 v1 = *(const float4*)(part + DPART + off);
    float4 v2 = *(const float4*)(part + 2 * DPART + off);
    float4 v3 = *(const float4*)(part + 3 * DPART + off);
    float4 v = { v0.x + v1.x + v2.x + v3.x, v0.y + v1.y + v2.y + v3.y,
                 v0.z + v1.z + v2.z + v3.z, v0.w + v1.w + v2.w + v3.w };
    u16* dst = bcat + ((long long)b * MAX_T + STARTP + l) * 576;
    if (t < 128) {
        u16x4 o = { f2b(v.x), f2b(v.y), f2b(v.z), f2b(v.w) };
        ((u16x4*)dst)[t] = o;
    } else {
        int g = t - 128;                  // pair group: pairs 2g, 2g+1
        float c0 = fc[l * 32 + 2 * g],     s0 = fs[l * 32 + 2 * g];
        float c1 = fc[l * 32 + 2 * g + 1], s1 = fs[l * 32 + 2 * g + 1];
        u16x4 o = { f2b(v.x * c0 - v.y * s0), f2b(v.x * s0 + v.y * c0),
                    f2b(v.z * c1 - v.w * s1), f2b(v.z * s1 + v.w * c1) };
        *(u16x4*)(dst + 512 + 4 * g) = o;
    }
}

// Latent cache prep: for t<4064 read fp32 kvc -> write bcat latent + kvcT;
// for t>=4064 read bcat (already written by bcat_new_reduce) -> write kvcT.
__global__ __launch_bounds__(256) void prep_cache(const float* __restrict__ kvc,
                                                  u16* __restrict__ bcat,
                                                  u16* __restrict__ kvcT)
{
    __shared__ u16 T[64][65];
    const int b = blockIdx.z;
    const int t0 = blockIdx.y * 64;
    const int k0 = blockIdx.x * 64;
    const int tid = threadIdx.x;
    #pragma unroll
    for (int i = 0; i < 16; ++i) {
        int lin = i * 256 + tid;
        int r = lin >> 6, c = lin & 63;   // r = t-row, c = k-col
        int t = t0 + r;
        u16 v;
        if (t < STARTP) {
            v = f2b(kvc[((long long)b * MAX_T + t) * KV_RANK + k0 + c]);
            bcat[((long long)b * MAX_T + t) * 576 + k0 + c] = v;
        } else {
            v = bcat[((long long)b * MAX_T + t) * 576 + k0 + c];
        }
        T[c][r] = v;
    }
    __syncthreads();
    u16* outp = kvcT + ((long long)b * KV_RANK + k0) * MAX_T + t0;
    #pragma unroll
    for (int i = 0; i < 16; ++i) {
        int lin = i * 256 + tid;
        int r = lin >> 6, c = lin & 63;   // r = k, c = t
        outp[(long long)r * MAX_T + c] = T[r][c];
    }
}

// roped q_rope (bf16 q in) -> qprimeb[b,h,l,512:576]
__global__ __launch_bounds__(256) void rope_q(const u16* __restrict__ qb,
                                              const float* __restrict__ fc,
                                              const float* __restrict__ fs,
                                              u16* __restrict__ qprimeb)
{
    int idx = blockIdx.x * 256 + threadIdx.x;
    int i = idx & 31;
    int h = (idx >> 5) & (NH - 1);
    int l = (idx >> 9) & (NL - 1);
    int b = idx >> 14;
    const u16* src = qb + (long long)(b * NL + l) * 3072 + h * QK_DIM + D_NR + 2 * i;
    float xr = b2f(src[0]), xi = b2f(src[1]);
    float c = fc[l * 32 + i], s = fs[l * 32 + i];
    u16* dst = qprimeb + ((long long)(b * NH + h) * NL + l) * 576 + 512 + 2 * i;
    dst[0] = f2b(xr * c - xi * s);
    dst[1] = f2b(xr * s + xi * c);
}

// Softmax: fp32 scores in, normalized bf16 P in place. Masked tail = 0.
__global__ __launch_bounds__(256) void softmax_bf16(float* __restrict__ scores)
{
    const int row = blockIdx.x;
    const int l = row & 31;
    const int vlen = STARTP + l + 1;
    float* s = scores + (long long)row * MAX_T;
    __shared__ float red[256];
    const int tid = threadIdx.x;

    float4 v[4];
    float m = -1e30f;
    #pragma unroll
    for (int i = 0; i < 4; ++i) {
        int f4 = i * 256 + tid;
        v[i] = ((const float4*)s)[f4];
        int t = f4 * 4;
        if (t + 0 >= vlen) v[i].x = -1e30f;
        if (t + 1 >= vlen) v[i].y = -1e30f;
        if (t + 2 >= vlen) v[i].z = -1e30f;
        if (t + 3 >= vlen) v[i].w = -1e30f;
        m = fmaxf(m, fmaxf(fmaxf(v[i].x, v[i].y), fmaxf(v[i].z, v[i].w)));
    }
    red[tid] = m; __syncthreads();
    for (int off = 128; off > 0; off >>= 1) {
        if (tid < off) red[tid] = fmaxf(red[tid], red[tid + off]);
        __syncthreads();
    }
    const float mm = red[0] * ATT_SCALE;
    __syncthreads();

    float sum = 0.f;
    #pragma unroll
    for (int i = 0; i < 4; ++i) {
        v[i].x = __expf(v[i].x * ATT_SCALE - mm);
        v[i].y = __expf(v[i].y * ATT_SCALE - mm);
        v[i].z = __expf(v[i].z * ATT_SCALE - mm);
        v[i].w = __expf(v[i].w * ATT_SCALE - mm);
        sum += v[i].x + v[i].y + v[i].z + v[i].w;
    }
    red[tid] = sum; __syncthreads();
    for (int off = 128; off > 0; off >>= 1) {
        if (tid < off) red[tid] += red[tid + off];
        __syncthreads();
    }
    const float inv = 1.0f / red[0];
    u16* ps = (u16*)s;
    #pragma unroll
    for (int i = 0; i < 4; ++i) {
        int f4 = i * 256 + tid;
        u16x4 o = { f2b(v[i].x * inv), f2b(v[i].y * inv), f2b(v[i].z * inv), f2b(v[i].w * inv) };
        ((u16x4*)ps)[f4] = o;
    }
}

// Sum 4 PV split-K partials -> bf16 o_hb. 524288 float4 groups total.
__global__ __launch_bounds__(256) void reduce_pv(const float* __restrict__ part,
                                                 u16* __restrict__ o_hb)
{
    int idx = blockIdx.x * 256 + threadIdx.x;     // < 524288
    int b = idx >> 16;
    int i4 = idx & 65535;
    const float* p = part + (long long)b * 1048576 + 4 * i4;
    float4 v0 = *(const float4*)p;
    float4 v1 = *(const float4*)(p + 262144);
    float4 v2 = *(const float4*)(p + 524288);
    float4 v3 = *(const float4*)(p + 786432);
    u16x4 o = { f2b(v0.x + v1.x + v2.x + v3.x), f2b(v0.y + v1.y + v2.y + v3.y),
                f2b(v0.z + v1.z + v2.z + v3.z), f2b(v0.w + v1.w + v2.w + v3.w) };
    ((u16x4*)(o_hb + (long long)b * 262144))[i4] = o;
}

// Sum 4 out-proj split-K partials -> fp32 out. 131072 float4 groups.
__global__ __launch_bounds__(256) void reduce_out(const float* __restrict__ part,
                                                  float* __restrict__ out)
{
    int idx = blockIdx.x * 256 + threadIdx.x;     // < 131072
    const float* p = part + 4 * (long long)idx;
    float4 v0 = *(const float4*)p;
    float4 v1 = *(const float4*)(p + 524288);
    float4 v2 = *(const float4*)(p + 1048576);
    float4 v3 = *(const float4*)(p + 1572864);
    float4 o = { v0.x + v1.x + v2.x + v3.x, v0.y + v1.y + v2.y + v3.y,
                 v0.z + v1.z + v2.z + v3.z, v0.w + v1.w + v2.w + v3.w };
    ((float4*)out)[idx] = o;
}

extern "C" void kernel_launch(void* const* d_in, const int* in_sizes, int n_in,
                              void* d_out, int out_size, void* d_ws, size_t ws_size,
                              hipStream_t stream)
{
    const float* x        = (const float*)d_in[0];
    const float* fc       = (const float*)d_in[2];
    const float* fs       = (const float*)d_in[3];
    const float* kvc      = (const float*)d_in[5];
    const float* krc      = (const float*)d_in[6];
    const float* w_kv_down= (const float*)d_in[7];
    const float* w_q_down = (const float*)d_in[8];
    const float* rms_q_w  = (const float*)d_in[9];
    const float* w_q_up   = (const float*)d_in[10];
    const float* w_kv_up  = (const float*)d_in[11];
    const float* w_out    = (const float*)d_in[12];
    float* out            = (float*)d_out;

    // ---- workspace layout ----
    float* down_part = (float*)d_ws;             // 4 x 256x1344 = 1376256 f
    float* scores  = down_part + 1376256;        // 16777216 f (bf16 P after softmax)
    u16* base      = (u16*)(scores + 16777216);
    u16* xb      = base;                 base += 524288;    // 256x2048
    u16* qdb     = base;                 base += 196608;    // 256x768
    u16* qb      = base;                 base += 786432;    // 256x3072
    u16* qprimeb = base;                 base += 2359296;   // (b,h,l,576)
    u16* wqkv_b  = base;                 base += 2752512;   // [w_q_down;w_kv_down] 1344x2048
    u16* wqu_b   = base;                 base += 2359296;   // 3072x768
    u16* wkvu_b  = base;                 base += 2097152;   // 4096x512
    u16* wout_b  = base;                 base += 4194304;   // 2048x2048
    u16* wuT     = base;                 base += 1048576;   // (h,512,128)
    u16* bcat    = base;                 base += 18874368;  // (b,4096,576)
    u16* kvcT    = base;                 base += 16777216;  // (b,512,4096)
    u16* o_hb    = base;                 base += 2097152;   // (b,512,512)
    u16* o_upb   = base;                 base += 524288;    // 256x2048
    // aliases over dead regions:
    float* pv_part  = (float*)bcat;   // 32 MB after scores GEMM
    float* out_part = (float*)kvcT;   // 8 MB after PV

    // 1) fp32->bf16 conversions (w_q_down and w_kv_down land adjacent in wqkv_b)
    Segs segs;
    segs.src[0] = x;         segs.dst[0] = xb;                  segs.n4[0] = 131072;
    segs.src[1] = w_q_down;  segs.dst[1] = wqkv_b;              segs.n4[1] = 393216;
    segs.src[2] = w_q_up;    segs.dst[2] = wqu_b;               segs.n4[2] = 589824;
    segs.src[3] = w_kv_down; segs.dst[3] = wqkv_b + 768 * 2048; segs.n4[3] = 294912;
    segs.src[4] = w_kv_up;   segs.dst[4] = wkvu_b;              segs.n4[4] = 524288;
    segs.src[5] = w_out;     segs.dst[5] = wout_b;              segs.n4[5] = 1048576;
    f2b_multi<<<dim3(4096, 6), 256, 0, stream>>>(segs);

    wuT_kernel<<<dim3(8, 2, 16), 256, 0, stream>>>(w_kv_up, wuT);
    bcat_rope_hist<<<(NB * STARTP * 16 + 255) / 256, 256, 0, stream>>>(krc, bcat);

    // 2) fused down-proj split-K=4: (256,1344,2048) -> down_part
    gemm_mfma<32, 64, false, true><<<dim3(21, 8, 4), 256, 0, stream>>>(
        xb, wqkv_b, down_part, 512, 2048, 2048, NDOWN,
        0LL, 512LL, 0LL, 512LL, 0LL, DPART, 4);
    // 3) reduce + RMS -> bf16
    rms_reduce<<<256, 256, 0, stream>>>(down_part, rms_q_w, qdb);
    // 4) q = qn @ w_q_up^T  (256,3072,768) bf16
    gemm_mfma<32, 64, true, true><<<dim3(48, 8, 1), 256, 0, stream>>>(
        qdb, wqu_b, qb, 768, 768, 768, 3072, 0, 0, 0, 0, 0, 0, 1);
    // 5) reduce kv part + write new bcat rows (latent + rope)
    bcat_new_reduce<<<256, 256, 0, stream>>>(down_part, fc, fs, bcat);
    // 6) latent cache: bcat hist cols + kvcT transpose in one pass
    prep_cache<<<dim3(8, 64, 8), 256, 0, stream>>>(kvc, bcat, kvcT);

    // 7) q_abs per (b,h) -> qprimeb[...,0:512]; rope -> [512:576]
    gemm_mfma<32, 128, true, true><<<dim3(4, 1, 128), 256, 0, stream>>>(
        qb, wuT, qprimeb, 128, 3072, 128, 576,
        98304LL, 192LL, 0LL, 65536LL, 294912LL, 18432LL, 16);
    rope_q<<<512, 256, 0, stream>>>(qb, fc, fs, qprimeb);

    // 8) scores = qprime @ bcat^T per b (512,4096,576)
    gemm_mfma<128, 128, false, true><<<dim3(32, 4, 8), 256, 0, stream>>>(
        qprimeb, bcat, scores, 576, 576, 576, 4096,
        294912LL, 0LL, 2359296LL, 0LL, 2097152LL, 0LL, 1);
    // 9) softmax -> bf16 P in place
    softmax_bf16<<<NB * NH * NL, 256, 0, stream>>>(scores);
    // 10) PV split-K=4: (512,512,4096) per b -> pv_part
    gemm_mfma<128, 128, false, true><<<dim3(4, 4, 32), 256, 0, stream>>>(
        (const u16*)scores, kvcT, pv_part, 1024, 8192, 4096, 512,
        4194304LL, 1024LL, 2097152LL, 1024LL, 1048576LL, 262144LL, 4);
    // 11) reduce -> bf16 o_hb
    reduce_pv<<<2048, 256, 0, stream>>>(pv_part, o_hb);

    // 12) o_up per (b,h): (32,128,512) bf16
    gemm_mfma<32, 64, true, true><<<dim3(2, 1, 128), 256, 0, stream>>>(
        o_hb, wkvu_b + 128 * 512, o_upb, 512, 512, 512, 2048,
        262144LL, 16384LL, 0LL, 131072LL, 65536LL, 128LL, 16);
    // 13) out-proj split-K=4: (256,2048,2048) -> out_part, reduce -> out
    gemm_mfma<32, 64, false, true><<<dim3(32, 8, 4), 256, 0, stream>>>(
        o_upb, wout_b, out_part, 512, 2048, 2048, 2048,
        0LL, 512LL, 0LL, 512LL, 0LL, 524288LL, 4);
    reduce_out<<<512, 256, 0, stream>>>(out_part, out);
}

// Round 6
// 323.125 us; speedup vs baseline: 5.1453x; 1.0491x over previous
//
#include <hip/hip_runtime.h>
#include <math.h>

#define DIMX 2048
#define KV_RANK 512
#define Q_RANK 768
#define NH 16
#define D_NR 128
#define D_R 64
#define D_V 128
#define NB 8
#define NL 32
#define MAX_T 4096
#define STARTP (MAX_T - NL)      /* 4064 */
#define QK_DIM (D_NR + D_R)      /* 192 */
#define ATT_SCALE 0.07216878364870323f  /* 1/sqrt(192) */
#define RMS_EPS 1.1920929e-07f

typedef unsigned short u16;
typedef __attribute__((ext_vector_type(4))) unsigned short u16x4;
typedef __attribute__((ext_vector_type(8))) short short8;
typedef __attribute__((ext_vector_type(4))) float f32x4;

#define GLOBAL_AS __attribute__((address_space(1)))
#define LDS_AS __attribute__((address_space(3)))

#define NDOWN 1344                 /* 768 + 576 fused down-proj N */
#define DPART ((long long)256 * NDOWN)   /* per-split partial stride */

__device__ inline u16 f2b(float f) {
    union { float f; unsigned u; } v; v.f = f;
    unsigned r = (v.u + 0x7fffu + ((v.u >> 16) & 1u)) >> 16;
    return (u16)r;
}
__device__ inline float b2f(u16 u) {
    union { unsigned u; float f; } v; v.u = ((unsigned)u) << 16; return v.f;
}

// ---------------------------------------------------------------------------
// bf16 MFMA GEMM, C = A * B^T (A (M,K), B (N,K), row-major bf16), fp32 acc.
// BM x BN tile, 4 waves (2x2). OUTB: bf16 C. GSWZ: XCD-chunked swizzle
// (requires total workgroups % 8 == 0): each XCD processes a CONTIGUOUS
// logical block range so blocks sharing A/B panels share one L2.
// Two-level batch: z1 = z/nb2, z2 = z%nb2. Split-K via z2 K-offset strides.
// ---------------------------------------------------------------------------
template<int BM, int BN, bool OUTB, bool GSWZ>
__global__ __launch_bounds__(256) void gemm_mfma(
    const u16* __restrict__ A, const u16* __restrict__ B, void* __restrict__ Cv,
    int K, int lda, int ldb, int ldc,
    long long sA1, long long sA2, long long sB1, long long sB2,
    long long sC1, long long sC2, int nb2)
{
    constexpr int MFR = BM / 32;
    constexpr int NFR = BN / 32;
    int bx = blockIdx.x, by = blockIdx.y, bz = blockIdx.z;
    if (GSWZ) {
        int flat = bx + gridDim.x * (by + gridDim.y * bz);
        int nwg = gridDim.x * gridDim.y * gridDim.z;
        int lf = (flat & 7) * (nwg >> 3) + (flat >> 3);
        bx = lf % gridDim.x;
        int r = lf / gridDim.x;
        by = r % gridDim.y;
        bz = r / gridDim.y;
    }
    const int z1 = bz / nb2, z2 = bz % nb2;
    A += z1 * sA1 + z2 * sA2;
    B += z1 * sB1 + z2 * sB2;

    const int m0 = by * BM;
    const int n0 = bx * BN;
    const int tid = threadIdx.x;
    const int lane = tid & 63;
    const int wid = tid >> 6;
    const int wm = wid >> 1, wn = wid & 1;
    const int l15 = lane & 15;
    const int l4  = lane >> 4;

    __shared__ __align__(16) u16 As[BM * 32];
    __shared__ __align__(16) u16 Bs[BN * 32];

    f32x4 acc[MFR][NFR];
    #pragma unroll
    for (int i = 0; i < MFR; ++i)
        #pragma unroll
        for (int j = 0; j < NFR; ++j)
            acc[i][j] = (f32x4)0.0f;

    constexpr int nA = BM / 16;
    constexpr int nB = BN / 16;

    for (int k0 = 0; k0 < K; k0 += 32) {
        #pragma unroll
        for (int j = 0; j < nA / 4 + 1; ++j) {
            int jj = wid + j * 4;
            if (jj < nA) {
                int c = jj * 64 + lane;
                const u16* src = A + (long long)(m0 + (c >> 2)) * lda + k0 + (c & 3) * 8;
                u16* dst = &As[jj * 512];
                __builtin_amdgcn_global_load_lds((const GLOBAL_AS void*)src,
                                                 (LDS_AS void*)dst, 16, 0, 0);
            }
        }
        #pragma unroll
        for (int j = 0; j < nB / 4 + 1; ++j) {
            int jj = wid + j * 4;
            if (jj < nB) {
                int c = jj * 64 + lane;
                const u16* src = B + (long long)(n0 + (c >> 2)) * ldb + k0 + (c & 3) * 8;
                u16* dst = &Bs[jj * 512];
                __builtin_amdgcn_global_load_lds((const GLOBAL_AS void*)src,
                                                 (LDS_AS void*)dst, 16, 0, 0);
            }
        }
        __syncthreads();

        short8 a[MFR], b[NFR];
        #pragma unroll
        for (int mf = 0; mf < MFR; ++mf)
            a[mf] = *(const short8*)&As[(wm * 16 * MFR + mf * 16 + l15) * 32 + l4 * 8];
        #pragma unroll
        for (int nf = 0; nf < NFR; ++nf)
            b[nf] = *(const short8*)&Bs[(wn * 16 * NFR + nf * 16 + l15) * 32 + l4 * 8];
        #pragma unroll
        for (int mf = 0; mf < MFR; ++mf)
            #pragma unroll
            for (int nf = 0; nf < NFR; ++nf)
                acc[mf][nf] = __builtin_amdgcn_mfma_f32_16x16x32_bf16(
                    a[mf], b[nf], acc[mf][nf], 0, 0, 0);
        __syncthreads();
    }

    if (OUTB) {
        u16* C = (u16*)Cv + z1 * sC1 + z2 * sC2;
        #pragma unroll
        for (int mf = 0; mf < MFR; ++mf)
            #pragma unroll
            for (int nf = 0; nf < NFR; ++nf) {
                int r0 = m0 + wm * 16 * MFR + mf * 16 + l4 * 4;
                int c0 = n0 + wn * 16 * NFR + nf * 16 + l15;
                #pragma unroll
                for (int r = 0; r < 4; ++r)
                    C[(long long)(r0 + r) * ldc + c0] = f2b(acc[mf][nf][r]);
            }
    } else {
        float* C = (float*)Cv + z1 * sC1 + z2 * sC2;
        #pragma unroll
        for (int mf = 0; mf < MFR; ++mf)
            #pragma unroll
            for (int nf = 0; nf < NFR; ++nf) {
                int r0 = m0 + wm * 16 * MFR + mf * 16 + l4 * 4;
                int c0 = n0 + wn * 16 * NFR + nf * 16 + l15;
                #pragma unroll
                for (int r = 0; r < 4; ++r)
                    C[(long long)(r0 + r) * ldc + c0] = acc[mf][nf][r];
            }
    }
}

// ---------------------------------------------------------------------------
struct Segs {
    const float* src[6];
    u16* dst[6];
    int n4[6];
};
__global__ __launch_bounds__(256) void f2b_multi(Segs s)
{
    int seg = blockIdx.y;
    int i = blockIdx.x * 256 + threadIdx.x;
    if (i >= s.n4[seg]) return;
    float4 v = ((const float4*)s.src[seg])[i];
    u16x4 o = { f2b(v.x), f2b(v.y), f2b(v.z), f2b(v.w) };
    ((u16x4*)s.dst[seg])[i] = o;
}

// Sum 4 split-K partials (cols 0..767 of fused down output), RMS-norm -> bf16.
__global__ __launch_bounds__(256) void rms_reduce(const float* __restrict__ part,
                                                  const float* __restrict__ w,
                                                  u16* __restrict__ outb)
{
    const int row = blockIdx.x;          // 0..255
    const int tid = threadIdx.x;
    __shared__ float red[256];
    float val[3];
    float s = 0.f;
    #pragma unroll
    for (int j = 0; j < 3; ++j) {
        int i = tid + j * 256;
        long long off = (long long)row * NDOWN + i;
        float v = part[off] + part[DPART + off] + part[2 * DPART + off] + part[3 * DPART + off];
        val[j] = v;
        s += v * v;
    }
    red[tid] = s; __syncthreads();
    for (int off = 128; off > 0; off >>= 1) {
        if (tid < off) red[tid] += red[tid + off];
        __syncthreads();
    }
    float scale = rsqrtf(red[0] / (float)Q_RANK + RMS_EPS);
    u16* ob = outb + (long long)row * Q_RANK;
    #pragma unroll
    for (int j = 0; j < 3; ++j) {
        int i = tid + j * 256;
        ob[i] = f2b(val[j] * scale * w[i]);
    }
}

// Transpose w_kv_up[:, :128] per head: fp32 (h,128,512) -> bf16 wuT (h,512,128)
__global__ __launch_bounds__(256) void wuT_kernel(const float* __restrict__ w,
                                                  u16* __restrict__ outp)
{
    __shared__ u16 T[64][65];
    const int h = blockIdx.z;
    const int y0 = blockIdx.y * 64;
    const int x0 = blockIdx.x * 64;
    const int tid = threadIdx.x;
    #pragma unroll
    for (int i = 0; i < 16; ++i) {
        int lin = i * 256 + tid;
        int r = lin >> 6, c = lin & 63;
        T[c][r] = f2b(w[((long long)h * 256 + y0 + r) * 512 + x0 + c]);
    }
    __syncthreads();
    #pragma unroll
    for (int i = 0; i < 16; ++i) {
        int lin = i * 256 + tid;
        int r = lin >> 6, c = lin & 63;
        outp[((long long)h * 512 + x0 + r) * 128 + y0 + c] = T[r][c];
    }
}

// Sum 4 kv split-K partials (cols 768.. of fused down output);
// write new bcat rows (latent + roped k_rope).
__global__ __launch_bounds__(256) void bcat_new_reduce(const float* __restrict__ part,
                                                       const float* __restrict__ fc,
                                                       const float* __restrict__ fs,
                                                       u16* __restrict__ bcat)
{
    const int bl = blockIdx.x;        // 0..255
    const int b = bl >> 5, l = bl & 31;
    const int t = threadIdx.x;
    if (t >= 144) return;
    long long off = (long long)bl * NDOWN + 768 + 4 * t;
    float4 v0 = *(const float4*)(part + off);
    float4 v1 = *(const float4*)(part + DPART + off);
    float4 v2 = *(const float4*)(part + 2 * DPART + off);
    float4 v3 = *(const float4*)(part + 3 * DPART + off);
    float4 v = { v0.x + v1.x + v2.x + v3.x, v0.y + v1.y + v2.y + v3.y,
                 v0.z + v1.z + v2.z + v3.z, v0.w + v1.w + v2.w + v3.w };
    u16* dst = bcat + ((long long)b * MAX_T + STARTP + l) * 576;
    if (t < 128) {
        u16x4 o = { f2b(v.x), f2b(v.y), f2b(v.z), f2b(v.w) };
        ((u16x4*)dst)[t] = o;
    } else {
        int g = t - 128;                  // pair group: pairs 2g, 2g+1
        float c0 = fc[l * 32 + 2 * g],     s0 = fs[l * 32 + 2 * g];
        float c1 = fc[l * 32 + 2 * g + 1], s1 = fs[l * 32 + 2 * g + 1];
        u16x4 o = { f2b(v.x * c0 - v.y * s0), f2b(v.x * s0 + v.y * c0),
                    f2b(v.z * c1 - v.w * s1), f2b(v.z * s1 + v.w * c1) };
        *(u16x4*)(dst + 512 + 4 * g) = o;
    }
}

// ---------------------------------------------------------------------------
// Fully-vectorized cache prep.
// Blocks bx<8: 64t x 64k transpose tile. t<4064: read fp32 kvc (float4),
//   write bcat latent (u16x4) + stage in LDS; t>=4064: read bcat (u16x4).
//   Then write kvcT rows (u16x4). LDS uses XOR swizzle on the t-group:
//   element (k,t) lives at T[k*64 + ((tg ^ (k>>2))<<2) + te], tg=t>>2, te=t&3.
// Block bx==8: rope history columns, fp32 krc float4 -> bcat[...,512:576].
// ---------------------------------------------------------------------------
__global__ __launch_bounds__(256) void prep_cache(const float* __restrict__ kvc,
                                                  const float* __restrict__ krc,
                                                  u16* __restrict__ bcat,
                                                  u16* __restrict__ kvcT)
{
    const int b = blockIdx.z;
    const int t0 = blockIdx.y * 64;
    const int tid = threadIdx.x;

    if (blockIdx.x == 8) {
        // rope history columns (new rows already written by bcat_new_reduce)
        #pragma unroll
        for (int i = 0; i < 4; ++i) {
            int lin = i * 256 + tid;
            int r = lin >> 4, c4 = lin & 15;
            int t = t0 + r;
            if (t >= STARTP) continue;
            float4 v = ((const float4*)(krc + ((long long)b * MAX_T + t) * D_R))[c4];
            u16x4 o = { f2b(v.x), f2b(v.y), f2b(v.z), f2b(v.w) };
            *(u16x4*)(bcat + ((long long)b * MAX_T + t) * 576 + 512 + 4 * c4) = o;
        }
        return;
    }

    __shared__ u16 T[64 * 64];
    const int k0 = blockIdx.x * 64;

    #pragma unroll
    for (int i = 0; i < 4; ++i) {
        int lin = i * 256 + tid;
        int r = lin >> 4, c4 = lin & 15;   // r = t-local, c4 = k float4-group
        int t = t0 + r;
        u16x4 o;
        if (t < STARTP) {
            float4 v = *(const float4*)(kvc + ((long long)b * MAX_T + t) * KV_RANK + k0 + 4 * c4);
            o.x = f2b(v.x); o.y = f2b(v.y); o.z = f2b(v.z); o.w = f2b(v.w);
            *(u16x4*)(bcat + ((long long)b * MAX_T + t) * 576 + k0 + 4 * c4) = o;
        } else {
            o = *(const u16x4*)(bcat + ((long long)b * MAX_T + t) * 576 + k0 + 4 * c4);
        }
        int tg = r >> 2, te = r & 3;
        int col = ((tg ^ c4) << 2) + te;   // (k>>2)&15 == c4 for k=4*c4+j
        #pragma unroll
        for (int j = 0; j < 4; ++j)
            T[(4 * c4 + j) * 64 + col] = o[j];
    }
    __syncthreads();

    u16* outp = kvcT + ((long long)b * KV_RANK + k0) * MAX_T + t0;
    #pragma unroll
    for (int i = 0; i < 4; ++i) {
        int lin = i * 256 + tid;
        int k = lin >> 4, c4 = lin & 15;   // k = k-local row, c4 = t float4-group
        u16x4 v = *(const u16x4*)&T[k * 64 + ((c4 ^ (k >> 2)) << 2)];
        *(u16x4*)(outp + (long long)k * MAX_T + 4 * c4) = v;
    }
}

// roped q_rope (bf16 q in) -> qprimeb[b,h,l,512:576]
__global__ __launch_bounds__(256) void rope_q(const u16* __restrict__ qb,
                                              const float* __restrict__ fc,
                                              const float* __restrict__ fs,
                                              u16* __restrict__ qprimeb)
{
    int idx = blockIdx.x * 256 + threadIdx.x;
    int i = idx & 31;
    int h = (idx >> 5) & (NH - 1);
    int l = (idx >> 9) & (NL - 1);
    int b = idx >> 14;
    const u16* src = qb + (long long)(b * NL + l) * 3072 + h * QK_DIM + D_NR + 2 * i;
    float xr = b2f(src[0]), xi = b2f(src[1]);
    float c = fc[l * 32 + i], s = fs[l * 32 + i];
    u16* dst = qprimeb + ((long long)(b * NH + h) * NL + l) * 576 + 512 + 2 * i;
    dst[0] = f2b(xr * c - xi * s);
    dst[1] = f2b(xr * s + xi * c);
}

// Softmax: fp32 scores in, normalized bf16 P in place. Masked tail = 0.
__global__ __launch_bounds__(256) void softmax_bf16(float* __restrict__ scores)
{
    const int row = blockIdx.x;
    const int l = row & 31;
    const int vlen = STARTP + l + 1;
    float* s = scores + (long long)row * MAX_T;
    __shared__ float red[256];
    const int tid = threadIdx.x;

    float4 v[4];
    float m = -1e30f;
    #pragma unroll
    for (int i = 0; i < 4; ++i) {
        int f4 = i * 256 + tid;
        v[i] = ((const float4*)s)[f4];
        int t = f4 * 4;
        if (t + 0 >= vlen) v[i].x = -1e30f;
        if (t + 1 >= vlen) v[i].y = -1e30f;
        if (t + 2 >= vlen) v[i].z = -1e30f;
        if (t + 3 >= vlen) v[i].w = -1e30f;
        m = fmaxf(m, fmaxf(fmaxf(v[i].x, v[i].y), fmaxf(v[i].z, v[i].w)));
    }
    red[tid] = m; __syncthreads();
    for (int off = 128; off > 0; off >>= 1) {
        if (tid < off) red[tid] = fmaxf(red[tid], red[tid + off]);
        __syncthreads();
    }
    const float mm = red[0] * ATT_SCALE;
    __syncthreads();

    float sum = 0.f;
    #pragma unroll
    for (int i = 0; i < 4; ++i) {
        v[i].x = __expf(v[i].x * ATT_SCALE - mm);
        v[i].y = __expf(v[i].y * ATT_SCALE - mm);
        v[i].z = __expf(v[i].z * ATT_SCALE - mm);
        v[i].w = __expf(v[i].w * ATT_SCALE - mm);
        sum += v[i].x + v[i].y + v[i].z + v[i].w;
    }
    red[tid] = sum; __syncthreads();
    for (int off = 128; off > 0; off >>= 1) {
        if (tid < off) red[tid] += red[tid + off];
        __syncthreads();
    }
    const float inv = 1.0f / red[0];
    u16* ps = (u16*)s;
    #pragma unroll
    for (int i = 0; i < 4; ++i) {
        int f4 = i * 256 + tid;
        u16x4 o = { f2b(v[i].x * inv), f2b(v[i].y * inv), f2b(v[i].z * inv), f2b(v[i].w * inv) };
        ((u16x4*)ps)[f4] = o;
    }
}

// Sum 4 PV split-K partials -> bf16 o_hb. 524288 float4 groups total.
__global__ __launch_bounds__(256) void reduce_pv(const float* __restrict__ part,
                                                 u16* __restrict__ o_hb)
{
    int idx = blockIdx.x * 256 + threadIdx.x;     // < 524288
    int b = idx >> 16;
    int i4 = idx & 65535;
    const float* p = part + (long long)b * 1048576 + 4 * i4;
    float4 v0 = *(const float4*)p;
    float4 v1 = *(const float4*)(p + 262144);
    float4 v2 = *(const float4*)(p + 524288);
    float4 v3 = *(const float4*)(p + 786432);
    u16x4 o = { f2b(v0.x + v1.x + v2.x + v3.x), f2b(v0.y + v1.y + v2.y + v3.y),
                f2b(v0.z + v1.z + v2.z + v3.z), f2b(v0.w + v1.w + v2.w + v3.w) };
    ((u16x4*)(o_hb + (long long)b * 262144))[i4] = o;
}

// Sum 4 out-proj split-K partials -> fp32 out. 131072 float4 groups.
__global__ __launch_bounds__(256) void reduce_out(const float* __restrict__ part,
                                                  float* __restrict__ out)
{
    int idx = blockIdx.x * 256 + threadIdx.x;     // < 131072
    const float* p = part + 4 * (long long)idx;
    float4 v0 = *(const float4*)p;
    float4 v1 = *(const float4*)(p + 524288);
    float4 v2 = *(const float4*)(p + 1048576);
    float4 v3 = *(const float4*)(p + 1572864);
    float4 o = { v0.x + v1.x + v2.x + v3.x, v0.y + v1.y + v2.y + v3.y,
                 v0.z + v1.z + v2.z + v3.z, v0.w + v1.w + v2.w + v3.w };
    ((float4*)out)[idx] = o;
}

extern "C" void kernel_launch(void* const* d_in, const int* in_sizes, int n_in,
                              void* d_out, int out_size, void* d_ws, size_t ws_size,
                              hipStream_t stream)
{
    const float* x        = (const float*)d_in[0];
    const float* fc       = (const float*)d_in[2];
    const float* fs       = (const float*)d_in[3];
    const float* kvc      = (const float*)d_in[5];
    const float* krc      = (const float*)d_in[6];
    const float* w_kv_down= (const float*)d_in[7];
    const float* w_q_down = (const float*)d_in[8];
    const float* rms_q_w  = (const float*)d_in[9];
    const float* w_q_up   = (const float*)d_in[10];
    const float* w_kv_up  = (const float*)d_in[11];
    const float* w_out    = (const float*)d_in[12];
    float* out            = (float*)d_out;

    // ---- workspace layout ----
    float* down_part = (float*)d_ws;             // 4 x 256x1344 = 1376256 f
    float* scores  = down_part + 1376256;        // 16777216 f (bf16 P after softmax)
    u16* base      = (u16*)(scores + 16777216);
    u16* xb      = base;                 base += 524288;    // 256x2048
    u16* qdb     = base;                 base += 196608;    // 256x768
    u16* qb      = base;                 base += 786432;    // 256x3072
    u16* qprimeb = base;                 base += 2359296;   // (b,h,l,576)
    u16* wqkv_b  = base;                 base += 2752512;   // [w_q_down;w_kv_down] 1344x2048
    u16* wqu_b   = base;                 base += 2359296;   // 3072x768
    u16* wkvu_b  = base;                 base += 2097152;   // 4096x512
    u16* wout_b  = base;                 base += 4194304;   // 2048x2048
    u16* wuT     = base;                 base += 1048576;   // (h,512,128)
    u16* bcat    = base;                 base += 18874368;  // (b,4096,576)
    u16* kvcT    = base;                 base += 16777216;  // (b,512,4096)
    u16* o_hb    = base;                 base += 2097152;   // (b,512,512)
    u16* o_upb   = base;                 base += 524288;    // 256x2048
    // aliases over dead regions:
    float* pv_part  = (float*)bcat;   // 32 MB after scores GEMM
    float* out_part = (float*)kvcT;   // 8 MB after PV

    // 1) fp32->bf16 conversions (w_q_down and w_kv_down land adjacent in wqkv_b)
    Segs segs;
    segs.src[0] = x;         segs.dst[0] = xb;                  segs.n4[0] = 131072;
    segs.src[1] = w_q_down;  segs.dst[1] = wqkv_b;              segs.n4[1] = 393216;
    segs.src[2] = w_q_up;    segs.dst[2] = wqu_b;               segs.n4[2] = 589824;
    segs.src[3] = w_kv_down; segs.dst[3] = wqkv_b + 768 * 2048; segs.n4[3] = 294912;
    segs.src[4] = w_kv_up;   segs.dst[4] = wkvu_b;              segs.n4[4] = 524288;
    segs.src[5] = w_out;     segs.dst[5] = wout_b;              segs.n4[5] = 1048576;
    f2b_multi<<<dim3(4096, 6), 256, 0, stream>>>(segs);

    wuT_kernel<<<dim3(8, 2, 16), 256, 0, stream>>>(w_kv_up, wuT);

    // 2) fused down-proj split-K=4: (256,1344,2048) -> down_part
    gemm_mfma<32, 64, false, true><<<dim3(21, 8, 4), 256, 0, stream>>>(
        xb, wqkv_b, down_part, 512, 2048, 2048, NDOWN,
        0LL, 512LL, 0LL, 512LL, 0LL, DPART, 4);
    // 3) reduce + RMS -> bf16
    rms_reduce<<<256, 256, 0, stream>>>(down_part, rms_q_w, qdb);
    // 4) q = qn @ w_q_up^T  (256,3072,768) bf16
    gemm_mfma<32, 64, true, true><<<dim3(48, 8, 1), 256, 0, stream>>>(
        qdb, wqu_b, qb, 768, 768, 768, 3072, 0, 0, 0, 0, 0, 0, 1);
    // 5) reduce kv part + write new bcat rows (latent + rope)
    bcat_new_reduce<<<256, 256, 0, stream>>>(down_part, fc, fs, bcat);
    // 6) cache prep: bcat hist (latent + rope cols) + kvcT transpose, vectorized
    prep_cache<<<dim3(9, 64, 8), 256, 0, stream>>>(kvc, krc, bcat, kvcT);

    // 7) q_abs per (b,h) -> qprimeb[...,0:512]; rope -> [512:576]
    gemm_mfma<32, 128, true, true><<<dim3(4, 1, 128), 256, 0, stream>>>(
        qb, wuT, qprimeb, 128, 3072, 128, 576,
        98304LL, 192LL, 0LL, 65536LL, 294912LL, 18432LL, 16);
    rope_q<<<512, 256, 0, stream>>>(qb, fc, fs, qprimeb);

    // 8) scores = qprime @ bcat^T per b (512,4096,576)
    gemm_mfma<128, 128, false, true><<<dim3(32, 4, 8), 256, 0, stream>>>(
        qprimeb, bcat, scores, 576, 576, 576, 4096,
        294912LL, 0LL, 2359296LL, 0LL, 2097152LL, 0LL, 1);
    // 9) softmax -> bf16 P in place
    softmax_bf16<<<NB * NH * NL, 256, 0, stream>>>(scores);
    // 10) PV split-K=4: (512,512,4096) per b -> pv_part
    gemm_mfma<128, 128, false, true><<<dim3(4, 4, 32), 256, 0, stream>>>(
        (const u16*)scores, kvcT, pv_part, 1024, 8192, 4096, 512,
        4194304LL, 1024LL, 2097152LL, 1024LL, 1048576LL, 262144LL, 4);
    // 11) reduce -> bf16 o_hb
    reduce_pv<<<2048, 256, 0, stream>>>(pv_part, o_hb);

    // 12) o_up per (b,h): (32,128,512) bf16
    gemm_mfma<32, 64, true, true><<<dim3(2, 1, 128), 256, 0, stream>>>(
        o_hb, wkvu_b + 128 * 512, o_upb, 512, 512, 512, 2048,
        262144LL, 16384LL, 0LL, 131072LL, 65536LL, 128LL, 16);
    // 13) out-proj split-K=4: (256,2048,2048) -> out_part, reduce -> out
    gemm_mfma<32, 64, false, true><<<dim3(32, 8, 4), 256, 0, stream>>>(
        o_upb, wout_b, out_part, 512, 2048, 2048, 2048,
        0LL, 512LL, 0LL, 512LL, 0LL, 524288LL, 4);
    reduce_out<<<512, 256, 0, stream>>>(out_part, out);
}